// Round 1
// baseline (1642.776 us; speedup 1.0000x reference)
//
#include <hip/hip_runtime.h>
#include <stdint.h>

#define N_ROWS 131072
#define DIMS 64
#define KCL 16
#define BETA 4.0f
#define NBLK 512            // N_ROWS / 256
#define CHUNK 8192          // elements per LDS sort chunk (8192 * 8B = 64KB LDS)
#define SORT_THREADS 512

typedef unsigned long long u64;
typedef unsigned int u32;

__device__ __forceinline__ u32 enc_f(float f) {
  u32 u = __float_as_uint(f);
  return (u & 0x80000000u) ? ~u : (u | 0x80000000u);
}
__device__ __forceinline__ float dec_f(u32 e) {
  u32 u = (e & 0x80000000u) ? (e & 0x7FFFFFFFu) : ~e;
  return __uint_as_float(u);
}

// ---------------- K1: cluster assign + softmax filling + per-block histograms
__global__ __launch_bounds__(256) void k_assign(
    const float* __restrict__ x, const float* __restrict__ centers,
    const int* __restrict__ predT, int* __restrict__ predX,
    float* __restrict__ fill_sum, u32* __restrict__ histX, u32* __restrict__ histT)
{
  __shared__ float c[KCL][DIMS];
  __shared__ float cn[KCL];
  __shared__ float fs[KCL];
  __shared__ u32 hx[KCL], ht[KCL];
  int tid = threadIdx.x;
  for (int t = tid; t < KCL * DIMS; t += 256) c[t / DIMS][t % DIMS] = centers[t];
  if (tid < KCL) { fs[tid] = 0.f; hx[tid] = 0; ht[tid] = 0; }
  __syncthreads();
  if (tid < KCL) {
    float s = 0.f;
    for (int d = 0; d < DIMS; ++d) s += c[tid][d] * c[tid][d];
    cn[tid] = s;
  }
  __syncthreads();
  int i = blockIdx.x * 256 + tid;
  const float4* xr = (const float4*)(x + (size_t)i * DIMS);
  float dot[KCL];
#pragma unroll
  for (int k = 0; k < KCL; ++k) dot[k] = 0.f;
  for (int t = 0; t < DIMS / 4; ++t) {
    float4 v = xr[t];
#pragma unroll
    for (int k = 0; k < KCL; ++k)
      dot[k] += v.x * c[k][4 * t] + v.y * c[k][4 * t + 1] + v.z * c[k][4 * t + 2] + v.w * c[k][4 * t + 3];
  }
  // score = ||c||^2 - 2 x.c   (||x||^2 cancels in both argmin and softmax)
  float sc[KCL];
  float smin = 3.0e38f; int kmin = 0;
#pragma unroll
  for (int k = 0; k < KCL; ++k) {
    sc[k] = cn[k] - 2.f * dot[k];
    if (sc[k] < smin) { smin = sc[k]; kmin = k; }
  }
  float e[KCL]; float esum = 0.f;
#pragma unroll
  for (int k = 0; k < KCL; ++k) { e[k] = expf(-BETA * (sc[k] - smin)); esum += e[k]; }
  float inv = 1.f / esum;
#pragma unroll
  for (int k = 0; k < KCL; ++k) atomicAdd(&fs[k], e[k] * inv);
  predX[i] = kmin;
  atomicAdd(&hx[kmin], 1u);
  atomicAdd(&ht[predT[i]], 1u);
  __syncthreads();
  if (tid < KCL) {
    histX[blockIdx.x * KCL + tid] = hx[tid];
    histT[blockIdx.x * KCL + tid] = ht[tid];
    atomicAdd(&fill_sum[tid], fs[tid]);
  }
}

// ---------------- K2: scan block histograms -> exclusive bases, totals, m, w, loss_fil
__global__ __launch_bounds__(512) void k_scan(
    const u32* __restrict__ histX, const u32* __restrict__ histT,
    u32* __restrict__ baseX, u32* __restrict__ baseT,
    const float* __restrict__ fill_sum, const float* __restrict__ ftarget,
    int* __restrict__ m_out, float* __restrict__ w_out, float* __restrict__ loss_fil)
{
  __shared__ u32 part[2][KCL][17];
  __shared__ u32 tot[2][KCL];
  __shared__ float sq[KCL];
  int tid = threadIdx.x;
  int side = tid >> 8;       // 0: X, 1: T
  int rem = tid & 255;
  int c = rem >> 4;          // cluster 0..15
  int sub = rem & 15;        // 16 threads per (side,cluster), 32 blocks each
  const u32* hist = side ? histT : histX;
  u32* base = side ? baseT : baseX;
  int b0 = sub * 32;
  u32 s = 0;
  for (int b = b0; b < b0 + 32; ++b) s += hist[b * KCL + c];
  part[side][c][sub] = s;
  __syncthreads();
  if (sub == 0) {
    u32 run = 0;
    for (int t = 0; t < 16; ++t) { u32 v = part[side][c][t]; part[side][c][t] = run; run += v; }
    tot[side][c] = run;
  }
  __syncthreads();
  u32 run = part[side][c][sub];
  for (int b = b0; b < b0 + 32; ++b) { base[b * KCL + c] = run; run += hist[b * KCL + c]; }
  if (tid < KCL) {
    int m = min((int)tot[0][tid], (int)tot[1][tid]);
    m_out[tid] = m;
    w_out[tid] = (m > 0) ? 1.f / ((float)m * (float)DIMS) : 0.f;
    float d = fill_sum[tid] / (float)N_ROWS - ftarget[tid];
    sq[tid] = d * d;
  }
  __syncthreads();
  if (tid == 0) {
    float s2 = 0.f;
    for (int k = 0; k < KCL; ++k) s2 += sq[k];
    *loss_fil = s2 / (float)KCL;
  }
}

// ---------------- K3: ordered within-cluster rank -> kept flags
__global__ __launch_bounds__(256) void k_kept(
    const int* __restrict__ predX, const int* __restrict__ predT,
    const u32* __restrict__ baseX, const u32* __restrict__ baseT,
    const int* __restrict__ m, unsigned char* __restrict__ keptX, unsigned char* __restrict__ keptT)
{
  __shared__ int wcX[4][KCL], wcT[4][KCL];
  int tid = threadIdx.x;
  int lane = tid & 63, wave = tid >> 6;
  int i = blockIdx.x * 256 + tid;
  int kx = predX[i], kt = predT[i];
  u64 below = (1ull << lane) - 1ull;
  int lrX = 0, lrT = 0;
  for (int cc = 0; cc < KCL; ++cc) {
    u64 mx = __ballot(kx == cc);
    u64 mt = __ballot(kt == cc);
    if (kx == cc) lrX = __popcll(mx & below);
    if (kt == cc) lrT = __popcll(mt & below);
    if (lane == 0) { wcX[wave][cc] = __popcll(mx); wcT[wave][cc] = __popcll(mt); }
  }
  __syncthreads();
  int wbX = 0, wbT = 0;
  for (int w2 = 0; w2 < wave; ++w2) { wbX += wcX[w2][kx]; wbT += wcT[w2][kt]; }
  int rX = (int)baseX[blockIdx.x * KCL + kx] + wbX + lrX;
  int rT = (int)baseT[blockIdx.x * KCL + kt] + wbT + lrT;
  keptX[i] = (rX < m[kx]) ? 1 : 0;
  keptT[i] = (rT < m[kt]) ? 1 : 0;
}

// ---------------- K4: build sort keys for a batch of dims (X segs 0..B-1, T segs B..2B-1)
__global__ __launch_bounds__(256) void k_build(
    const float* __restrict__ x, const float* __restrict__ tgt,
    const int* __restrict__ predX, const int* __restrict__ predT,
    const unsigned char* __restrict__ keptX, const unsigned char* __restrict__ keptT,
    u64* __restrict__ keys, int d0, int B)
{
  int i = blockIdx.x * 256 + threadIdx.x;
  int kx = predX[i], kt = predT[i];
  bool okx = keptX[i] != 0, okt = keptT[i] != 0;
  u64 hiX = ((u64)(u32)kx) << 32;
  u64 hiT = ((u64)(u32)kt) << 32;
  const float* xr = x + (size_t)i * DIMS + d0;
  const float* tr = tgt + (size_t)i * DIMS + d0;
  for (int d = 0; d < B; ++d) {
    u64 keyx = okx ? (hiX | (u64)enc_f(xr[d])) : ~0ull;
    u64 keyt = okt ? (hiT | (u64)enc_f(tr[d])) : ~0ull;
    keys[(size_t)d * N_ROWS + i] = keyx;
    keys[(size_t)(B + d) * N_ROWS + i] = keyt;
  }
}

// ---------------- K5: LDS bitonic sort of CHUNK-sized chunks (stages k<=CHUNK)
__global__ __launch_bounds__(SORT_THREADS) void k_sort_local(u64* __restrict__ keys)
{
  __shared__ u64 a[CHUNK];
  int tid = threadIdx.x;
  int chunksPerSeg = N_ROWS / CHUNK;
  int seg = blockIdx.x / chunksPerSeg;
  int cis = blockIdx.x % chunksPerSeg;
  size_t base = (size_t)seg * N_ROWS + (size_t)cis * CHUNK;
  int gb = cis * CHUNK;
  for (int t = tid; t < CHUNK; t += SORT_THREADS) a[t] = keys[base + t];
  __syncthreads();
  for (int k = 2; k <= CHUNK; k <<= 1) {
    for (int j = k >> 1; j > 0; j >>= 1) {
      for (int t = tid; t < CHUNK / 2; t += SORT_THREADS) {
        int i = ((t & ~(j - 1)) << 1) | (t & (j - 1));
        int l = i | j;
        bool up = (((gb + i) & k) == 0);
        u64 A = a[i], Bv = a[l];
        if ((A > Bv) == up) { a[i] = Bv; a[l] = A; }
      }
      __syncthreads();
    }
  }
  for (int t = tid; t < CHUNK; t += SORT_THREADS) keys[base + t] = a[t];
}

// ---------------- K6: one global bitonic pass (stage kk, stride j >= CHUNK)
__global__ __launch_bounds__(256) void k_sort_global(u64* __restrict__ keys, int kk, int j, int nseg)
{
  size_t t = (size_t)blockIdx.x * 256 + threadIdx.x;
  const int perSeg = N_ROWS / 2;
  int seg = (int)(t / perSeg);
  int u = (int)(t % perSeg);
  if (seg >= nseg) return;
  int i = ((u & ~(j - 1)) << 1) | (u & (j - 1));
  int l = i | j;
  bool up = ((i & kk) == 0);
  size_t bi = (size_t)seg * N_ROWS;
  u64 A = keys[bi + i], Bv = keys[bi + l];
  if ((A > Bv) == up) { keys[bi + i] = Bv; keys[bi + l] = A; }
}

// ---------------- K7: finish a stage (kk > CHUNK) for strides <= CHUNK/2 in LDS
__global__ __launch_bounds__(SORT_THREADS) void k_sort_finish(u64* __restrict__ keys, int kk)
{
  __shared__ u64 a[CHUNK];
  int tid = threadIdx.x;
  int chunksPerSeg = N_ROWS / CHUNK;
  int seg = blockIdx.x / chunksPerSeg;
  int cis = blockIdx.x % chunksPerSeg;
  size_t base = (size_t)seg * N_ROWS + (size_t)cis * CHUNK;
  bool up = (((cis * CHUNK) & kk) == 0);   // uniform per chunk since kk > CHUNK
  for (int t = tid; t < CHUNK; t += SORT_THREADS) a[t] = keys[base + t];
  __syncthreads();
  for (int j = CHUNK >> 1; j > 0; j >>= 1) {
    for (int t = tid; t < CHUNK / 2; t += SORT_THREADS) {
      int i = ((t & ~(j - 1)) << 1) | (t & (j - 1));
      int l = i | j;
      u64 A = a[i], Bv = a[l];
      if ((A > Bv) == up) { a[i] = Bv; a[l] = A; }
    }
    __syncthreads();
  }
  for (int t = tid; t < CHUNK; t += SORT_THREADS) keys[base + t] = a[t];
}

// ---------------- K8: pair sorted X/T segments positionally, accumulate weighted |diff|
__global__ __launch_bounds__(256) void k_reduce(
    const u64* __restrict__ keys, const float* __restrict__ w,
    float* __restrict__ lossAcc, int B)
{
  __shared__ float red[256];
  size_t total = (size_t)B * N_ROWS;
  float s = 0.f;
  for (size_t t = (size_t)blockIdx.x * 256 + threadIdx.x; t < total; t += (size_t)gridDim.x * 256) {
    size_t d = t / N_ROWS;
    size_t j = t % N_ROWS;
    u64 kx = keys[d * N_ROWS + j];
    u32 cx = (u32)(kx >> 32);
    if (cx < KCL) {
      u64 kt = keys[(size_t)(B + d) * N_ROWS + j];
      float vx = dec_f((u32)kx);
      float vt = dec_f((u32)kt);
      s += fabsf(vx - vt) * w[cx];
    }
  }
  red[threadIdx.x] = s;
  __syncthreads();
  for (int st = 128; st > 0; st >>= 1) {
    if (threadIdx.x < st) red[threadIdx.x] += red[threadIdx.x + st];
    __syncthreads();
  }
  if (threadIdx.x == 0) atomicAdd(lossAcc, red[0]);
}

// ---------------- K9: final scalar
__global__ void k_final(const float* __restrict__ lossAcc, const float* __restrict__ loss_fil,
                        float* __restrict__ out)
{
  out[0] = *lossAcc + *loss_fil;
}

extern "C" void kernel_launch(void* const* d_in, const int* in_sizes, int n_in,
                              void* d_out, int out_size, void* d_ws, size_t ws_size,
                              hipStream_t stream)
{
  const float* x       = (const float*)d_in[0];
  const float* centers = (const float*)d_in[1];
  const float* ftarget = (const float*)d_in[2];
  const float* tgt     = (const float*)d_in[3];
  const int*   predT   = (const int*)d_in[4];
  float* out = (float*)d_out;

  char* ws = (char*)d_ws;
  float* fill_sum = (float*)(ws + 0);      // 16 floats (zeroed)
  float* lossAcc  = (float*)(ws + 64);     // 1 float  (zeroed)
  float* loss_fil = (float*)(ws + 128);    // 1 float  (zeroed)
  int*   m_buf    = (int*)(ws + 192);      // 16 ints
  float* w_buf    = (float*)(ws + 256);    // 16 floats
  u32* histX = (u32*)(ws + 512);                     // 512*16*4 = 32768
  u32* histT = (u32*)(ws + 512 + 32768);
  u32* baseX = (u32*)(ws + 512 + 65536);
  u32* baseT = (u32*)(ws + 512 + 98304);
  int* predX = (int*)(ws + 132096);                  // 131072*4 = 524288
  unsigned char* keptX = (unsigned char*)(ws + 132096 + 524288);
  unsigned char* keptT = keptX + N_ROWS;
  const size_t keys_off = 1u << 20;
  u64* keys = (u64*)(ws + keys_off);

  // dim-batch size that fits workspace (full 64 dims needs ~129 MB)
  size_t avail = (ws_size > keys_off) ? (ws_size - keys_off) : 0;
  int B = (int)(avail / (2ull * N_ROWS * 8ull));
  if (B > DIMS) B = DIMS;
  if (B < 1) B = 1;

  hipMemsetAsync(ws, 0, 192, stream);
  k_assign<<<NBLK, 256, 0, stream>>>(x, centers, predT, predX, fill_sum, histX, histT);
  k_scan<<<1, 512, 0, stream>>>(histX, histT, baseX, baseT, fill_sum, ftarget, m_buf, w_buf, loss_fil);
  k_kept<<<NBLK, 256, 0, stream>>>(predX, predT, baseX, baseT, m_buf, keptX, keptT);

  for (int d0 = 0; d0 < DIMS; d0 += B) {
    int Bc = (B < DIMS - d0) ? B : (DIMS - d0);
    int nseg = 2 * Bc;
    int nchunks = nseg * (N_ROWS / CHUNK);
    k_build<<<NBLK, 256, 0, stream>>>(x, tgt, predX, predT, keptX, keptT, keys, d0, Bc);
    k_sort_local<<<nchunks, SORT_THREADS, 0, stream>>>(keys);
    for (int kk = CHUNK * 2; kk <= N_ROWS; kk <<= 1) {
      for (int j = kk >> 1; j >= CHUNK; j >>= 1) {
        int blocks = (int)(((size_t)nseg * (N_ROWS / 2) + 255) / 256);
        k_sort_global<<<blocks, 256, 0, stream>>>(keys, kk, j, nseg);
      }
      k_sort_finish<<<nchunks, SORT_THREADS, 0, stream>>>(keys, kk);
    }
    k_reduce<<<2048, 256, 0, stream>>>(keys, w_buf, lossAcc, Bc);
  }
  k_final<<<1, 1, 0, stream>>>(lossAcc, loss_fil, out);
}

// Round 2
// 1555.274 us; speedup vs baseline: 1.0563x; 1.0563x over previous
//
#include <hip/hip_runtime.h>
#include <stdint.h>

#define N_ROWS 131072
#define DIMS 64
#define KCL 16
#define BETA 4.0f
#define NBLK 512            // N_ROWS / 256
#define CHMAX 16384         // max elements per LDS sort chunk (16384 * 4B = 64KB)
#define LST 512
#define SEG_STRIDE 263168   // u32 elements per (dim,side): >= 2N + 16*32 padding
#define VOFF (1u<<21)

typedef unsigned long long u64;
typedef unsigned int u32;

__device__ __forceinline__ u32 enc_f(float f) {
  u32 u = __float_as_uint(f);
  return (u & 0x80000000u) ? ~u : (u | 0x80000000u);
}
__device__ __forceinline__ float dec_f(u32 e) {
  u32 u = (e & 0x80000000u) ? (e & 0x7FFFFFFFu) : ~e;
  return __uint_as_float(u);
}
__device__ __forceinline__ u32 swz(u32 e) { return e ^ ((e >> 5) & 31u); }

__device__ __forceinline__ void cswap(u32 &a, u32 &b, bool up) {
  u32 mn = min(a, b), mx = max(a, b);
  a = up ? mn : mx;
  b = up ? mx : mn;
}

// bitonic merge network on 32 regs, fixed direction (strides 16..1)
__device__ __forceinline__ void netmerge32(u32 r[32], bool up) {
#pragma unroll
  for (int j = 16; j >= 1; j >>= 1) {
#pragma unroll
    for (int t = 0; t < 16; ++t) {
      int i = ((t & ~(j - 1)) << 1) | (t & (j - 1));
      cswap(r[i], r[i | j], up);
    }
  }
}

// full bitonic sort of 32 regs; final direction upFinal
__device__ __forceinline__ void netsort32(u32 r[32], bool upFinal) {
#pragma unroll
  for (int k = 2; k <= 16; k <<= 1) {
#pragma unroll
    for (int j = k >> 1; j >= 1; j >>= 1) {
#pragma unroll
      for (int t = 0; t < 16; ++t) {
        int i = ((t & ~(j - 1)) << 1) | (t & (j - 1));
        cswap(r[i], r[i | j], ((i & k) == 0));
      }
    }
  }
  netmerge32(r, upFinal);
}

// ---------------- K1: cluster assign + softmax filling + per-block histograms
__global__ __launch_bounds__(256) void k_assign(
    const float* __restrict__ x, const float* __restrict__ centers,
    const int* __restrict__ predT, int* __restrict__ predX,
    float* __restrict__ fill_sum, u32* __restrict__ histX, u32* __restrict__ histT)
{
  __shared__ float c[KCL][DIMS];
  __shared__ float cn[KCL];
  __shared__ float fs[KCL];
  __shared__ u32 hx[KCL], ht[KCL];
  int tid = threadIdx.x;
  for (int t = tid; t < KCL * DIMS; t += 256) c[t / DIMS][t % DIMS] = centers[t];
  if (tid < KCL) { fs[tid] = 0.f; hx[tid] = 0; ht[tid] = 0; }
  __syncthreads();
  if (tid < KCL) {
    float s = 0.f;
    for (int d = 0; d < DIMS; ++d) s += c[tid][d] * c[tid][d];
    cn[tid] = s;
  }
  __syncthreads();
  int i = blockIdx.x * 256 + tid;
  const float4* xr = (const float4*)(x + (size_t)i * DIMS);
  float dot[KCL];
#pragma unroll
  for (int k = 0; k < KCL; ++k) dot[k] = 0.f;
  for (int t = 0; t < DIMS / 4; ++t) {
    float4 v = xr[t];
#pragma unroll
    for (int k = 0; k < KCL; ++k)
      dot[k] += v.x * c[k][4 * t] + v.y * c[k][4 * t + 1] + v.z * c[k][4 * t + 2] + v.w * c[k][4 * t + 3];
  }
  float sc[KCL];
  float smin = 3.0e38f; int kmin = 0;
#pragma unroll
  for (int k = 0; k < KCL; ++k) {
    sc[k] = cn[k] - 2.f * dot[k];
    if (sc[k] < smin) { smin = sc[k]; kmin = k; }
  }
  float e[KCL]; float esum = 0.f;
#pragma unroll
  for (int k = 0; k < KCL; ++k) { e[k] = expf(-BETA * (sc[k] - smin)); esum += e[k]; }
  float inv = 1.f / esum;
#pragma unroll
  for (int k = 0; k < KCL; ++k) atomicAdd(&fs[k], e[k] * inv);
  predX[i] = kmin;
  atomicAdd(&hx[kmin], 1u);
  atomicAdd(&ht[predT[i]], 1u);
  __syncthreads();
  if (tid < KCL) {
    histX[blockIdx.x * KCL + tid] = hx[tid];
    histT[blockIdx.x * KCL + tid] = ht[tid];
    atomicAdd(&fill_sum[tid], fs[tid]);
  }
}

// ---------------- K2: scan hists -> bases, totals, m, w, p (pow2 pad), pOff, loss_fil
__global__ __launch_bounds__(512) void k_scan(
    const u32* __restrict__ histX, const u32* __restrict__ histT,
    u32* __restrict__ baseX, u32* __restrict__ baseT,
    const float* __restrict__ fill_sum, const float* __restrict__ ftarget,
    int* __restrict__ m_out, float* __restrict__ w_out,
    int* __restrict__ p_out, int* __restrict__ pOff_out, float* __restrict__ loss_fil)
{
  __shared__ u32 part[2][KCL][17];
  __shared__ u32 tot[2][KCL];
  __shared__ float sq[KCL];
  __shared__ int sp[KCL];
  int tid = threadIdx.x;
  int side = tid >> 8;
  int rem = tid & 255;
  int c = rem >> 4;
  int sub = rem & 15;
  const u32* hist = side ? histT : histX;
  u32* base = side ? baseT : baseX;
  int b0 = sub * 32;
  u32 s = 0;
  for (int b = b0; b < b0 + 32; ++b) s += hist[b * KCL + c];
  part[side][c][sub] = s;
  __syncthreads();
  if (sub == 0) {
    u32 run = 0;
    for (int t = 0; t < 16; ++t) { u32 v = part[side][c][t]; part[side][c][t] = run; run += v; }
    tot[side][c] = run;
  }
  __syncthreads();
  u32 run = part[side][c][sub];
  for (int b = b0; b < b0 + 32; ++b) { base[b * KCL + c] = run; run += hist[b * KCL + c]; }
  if (tid < KCL) {
    int m = min((int)tot[0][tid], (int)tot[1][tid]);
    m_out[tid] = m;
    w_out[tid] = (m > 0) ? 1.f / ((float)m * (float)DIMS) : 0.f;
    int pp = 32;
    while (pp < m) pp <<= 1;
    sp[tid] = pp;
    p_out[tid] = pp;
    float d = fill_sum[tid] / (float)N_ROWS - ftarget[tid];
    sq[tid] = d * d;
  }
  __syncthreads();
  if (tid == 0) {
    float s2 = 0.f;
    int acc = 0;
    for (int k = 0; k < KCL; ++k) {
      s2 += sq[k];
      pOff_out[k] = acc;
      acc += sp[k];
    }
    pOff_out[KCL] = acc;
    *loss_fil = s2 / (float)KCL;
  }
}

// ---------------- K3: ordered within-cluster rank (-1 if not kept)
__global__ __launch_bounds__(256) void k_rank(
    const int* __restrict__ predX, const int* __restrict__ predT,
    const u32* __restrict__ baseX, const u32* __restrict__ baseT,
    const int* __restrict__ m, int* __restrict__ rankX, int* __restrict__ rankT)
{
  __shared__ int wcX[4][KCL], wcT[4][KCL];
  int tid = threadIdx.x;
  int lane = tid & 63, wave = tid >> 6;
  int i = blockIdx.x * 256 + tid;
  int kx = predX[i], kt = predT[i];
  u64 below = (1ull << lane) - 1ull;
  int lrX = 0, lrT = 0;
  for (int cc = 0; cc < KCL; ++cc) {
    u64 mx = __ballot(kx == cc);
    u64 mt = __ballot(kt == cc);
    if (kx == cc) lrX = __popcll(mx & below);
    if (kt == cc) lrT = __popcll(mt & below);
    if (lane == 0) { wcX[wave][cc] = __popcll(mx); wcT[wave][cc] = __popcll(mt); }
  }
  __syncthreads();
  int wbX = 0, wbT = 0;
  for (int w2 = 0; w2 < wave; ++w2) { wbX += wcX[w2][kx]; wbT += wcT[w2][kt]; }
  int rX = (int)baseX[blockIdx.x * KCL + kx] + wbX + lrX;
  int rT = (int)baseT[blockIdx.x * KCL + kt] + wbT + lrT;
  rankX[i] = (rX < m[kx]) ? rX : -1;
  rankT[i] = (rT < m[kt]) ? rT : -1;
}

// ---------------- K4: scatter kept encoded values into cluster-partitioned dim arrays
__global__ __launch_bounds__(256) void k_scatter(
    const float* __restrict__ x, const float* __restrict__ tgt,
    const int* __restrict__ predX, const int* __restrict__ predT,
    const int* __restrict__ rankX, const int* __restrict__ rankT,
    const int* __restrict__ pOffG,
    u32* __restrict__ valX, u32* __restrict__ valT, int d0, int Dbc)
{
  __shared__ int spOff[KCL + 1];
  int tid = threadIdx.x;
  if (tid <= KCL) spOff[tid] = pOffG[tid];
  __syncthreads();
  int i = blockIdx.x * 256 + tid;
  int cx = predX[i], rx = rankX[i];
  int ct = predT[i], rt = rankT[i];
  if (rx >= 0) {
    size_t pos = (size_t)spOff[cx] + rx;
    const float* xr = x + (size_t)i * DIMS + d0;
    for (int d = 0; d < Dbc; ++d) valX[(size_t)d * SEG_STRIDE + pos] = enc_f(xr[d]);
  }
  if (rt >= 0) {
    size_t pos = (size_t)spOff[ct] + rt;
    const float* tr = tgt + (size_t)i * DIMS + d0;
    for (int d = 0; d < Dbc; ++d) valT[(size_t)d * SEG_STRIDE + pos] = enc_f(tr[d]);
  }
}

// ---------------- K5: per-segment LDS sort (register-tiled bitonic, up to 16K elems)
__global__ __launch_bounds__(LST) void k_local_sort(
    u32* __restrict__ valX, u32* __restrict__ valT,
    const int* __restrict__ pG, const int* __restrict__ pOffG, int Dbc)
{
  __shared__ u32 lds[CHMAX];
  int sd = blockIdx.y;
  u32* base = (sd < Dbc) ? (valX + (size_t)sd * SEG_STRIDE)
                         : (valT + (size_t)(sd - Dbc) * SEG_STRIDE);
  // map blockIdx.x -> (cluster, chunk-within-cluster)
  int t = blockIdx.x, c = -1, sub = 0, acc = 0;
  for (int cc = 0; cc < KCL; ++cc) {
    int pc = pG[cc];
    int nc = (pc > CHMAX) ? (pc / CHMAX) : 1;
    if (t < acc + nc) { c = cc; sub = t - acc; break; }
    acc += nc;
  }
  if (c < 0) return;
  int pc = pG[c];
  u32 CH = (u32)min(pc, CHMAX);
  u32 gb = (u32)sub * (u32)CHMAX;      // chunk base within segment
  u32* seg = base + pOffG[c] + gb;
  int tid = threadIdx.x;

  for (u32 e = tid; e < CH; e += LST) lds[swz(e)] = seg[e];
  __syncthreads();

  // stages k<=32 in registers
  if ((u32)tid * 32u < CH) {
    u32 b = (u32)tid * 32u;
    u32 r[32];
#pragma unroll
    for (int q = 0; q < 32; ++q) r[q] = lds[swz(b + q)];
    netsort32(r, (((gb + b) & 32u) == 0));
#pragma unroll
    for (int q = 0; q < 32; ++q) lds[swz(b + q)] = r[q];
  }
  __syncthreads();

  // merge stages k=64..CH: LDS passes j>=32, register sweep j=16..1
  for (u32 k = 64; k <= CH; k <<= 1) {
    for (u32 j = k >> 1; j >= 32; j >>= 1) {
      for (u32 tt = tid; tt < (CH >> 1); tt += LST) {
        u32 i = ((tt & ~(j - 1)) << 1) | (tt & (j - 1));
        u32 l = i | j;
        bool up = (((gb + i) & k) == 0);
        u32 ei = swz(i), el = swz(l);
        u32 A = lds[ei], Bv = lds[el];
        u32 mn = min(A, Bv), mx = max(A, Bv);
        lds[ei] = up ? mn : mx;
        lds[el] = up ? mx : mn;
      }
      __syncthreads();
    }
    if ((u32)tid * 32u < CH) {
      u32 b = (u32)tid * 32u;
      u32 r[32];
#pragma unroll
      for (int q = 0; q < 32; ++q) r[q] = lds[swz(b + q)];
      netmerge32(r, (((gb + b) & k) == 0));
#pragma unroll
      for (int q = 0; q < 32; ++q) lds[swz(b + q)] = r[q];
    }
    __syncthreads();
  }

  for (u32 e = tid; e < CH; e += LST) seg[e] = lds[swz(e)];
}

// ---------------- K6: global bitonic pass for big segments (early-exit fallback)
__global__ __launch_bounds__(256) void k_gpass(
    u32* __restrict__ valX, u32* __restrict__ valT,
    const int* __restrict__ pG, const int* __restrict__ pOffG, int kk, int j, int Dbc)
{
  int sd = blockIdx.y;
  u32* base = (sd < Dbc) ? (valX + (size_t)sd * SEG_STRIDE)
                         : (valT + (size_t)(sd - Dbc) * SEG_STRIDE);
  int pb[KCL]; int tot = 0;
#pragma unroll
  for (int c = 0; c < KCL; ++c) {
    pb[c] = tot;
    int pc = pG[c];
    if (pc >= kk) tot += pc >> 1;
  }
  for (int g = blockIdx.x * 256 + threadIdx.x; g < tot; g += gridDim.x * 256) {
    int c = 0;
#pragma unroll
    for (int cc = 1; cc < KCL; ++cc) c += (g >= pb[cc]) ? 1 : 0;
    int u = g - pb[c];
    int i = ((u & ~(j - 1)) << 1) | (u & (j - 1));
    int l = i | j;
    bool up = ((i & kk) == 0);
    u32* s2 = base + pOffG[c];
    u32 A = s2[i], Bv = s2[l];
    if ((A > Bv) == up) { s2[i] = Bv; s2[l] = A; }
  }
}

// ---------------- K7: finish a big-segment stage (strides <=8192) in LDS
__global__ __launch_bounds__(LST) void k_gfinish(
    u32* __restrict__ valX, u32* __restrict__ valT,
    const int* __restrict__ pG, const int* __restrict__ pOffG, int kk, int Dbc)
{
  __shared__ u32 lds[CHMAX];
  int sd = blockIdx.y;
  u32* base = (sd < Dbc) ? (valX + (size_t)sd * SEG_STRIDE)
                         : (valT + (size_t)(sd - Dbc) * SEG_STRIDE);
  int t = blockIdx.x, c = -1, sub = 0, acc = 0;
  for (int cc = 0; cc < KCL; ++cc) {
    int pc = pG[cc];
    if (pc < kk) continue;
    int nc = pc / CHMAX;
    if (t < acc + nc) { c = cc; sub = t - acc; break; }
    acc += nc;
  }
  if (c < 0) return;
  u32 gbseg = (u32)sub * (u32)CHMAX;
  bool up = ((gbseg & (u32)kk) == 0);
  u32* seg = base + pOffG[c] + gbseg;
  int tid = threadIdx.x;

  for (u32 e = tid; e < CHMAX; e += LST) lds[swz(e)] = seg[e];
  __syncthreads();
  for (u32 j = CHMAX >> 1; j >= 32; j >>= 1) {
    for (u32 tt = tid; tt < (CHMAX >> 1); tt += LST) {
      u32 i = ((tt & ~(j - 1)) << 1) | (tt & (j - 1));
      u32 l = i | j;
      u32 ei = swz(i), el = swz(l);
      u32 A = lds[ei], Bv = lds[el];
      u32 mn = min(A, Bv), mx = max(A, Bv);
      lds[ei] = up ? mn : mx;
      lds[el] = up ? mx : mn;
    }
    __syncthreads();
  }
  {
    u32 b = (u32)tid * 32u;
    u32 r[32];
#pragma unroll
    for (int q = 0; q < 32; ++q) r[q] = lds[swz(b + q)];
    netmerge32(r, up);
#pragma unroll
    for (int q = 0; q < 32; ++q) lds[swz(b + q)] = r[q];
  }
  __syncthreads();
  for (u32 e = tid; e < CHMAX; e += LST) seg[e] = lds[swz(e)];
}

// ---------------- K8: pair sorted X/T per (cluster,dim), weighted |diff| reduce
__global__ __launch_bounds__(256) void k_reduce(
    const u32* __restrict__ valX, const u32* __restrict__ valT,
    const int* __restrict__ pOffG, const int* __restrict__ mG,
    const float* __restrict__ wG, float* __restrict__ lossAcc, int Dbc)
{
  __shared__ int spOff[KCL + 1];
  __shared__ int sm[KCL];
  __shared__ float swt[KCL];
  __shared__ float red[256];
  int tid = threadIdx.x;
  if (tid <= KCL) spOff[tid] = pOffG[tid];
  if (tid < KCL) { sm[tid] = mG[tid]; swt[tid] = wG[tid]; }
  __syncthreads();
  int d = blockIdx.y;
  const u32* vx = valX + (size_t)d * SEG_STRIDE;
  const u32* vt = valT + (size_t)d * SEG_STRIDE;
  int P16 = spOff[KCL];
  float s = 0.f;
  for (int pos = blockIdx.x * 256 + tid; pos < P16; pos += gridDim.x * 256) {
    int c = 0;
#pragma unroll
    for (int cc = 1; cc < KCL; ++cc) c += (pos >= spOff[cc]) ? 1 : 0;
    int rel = pos - spOff[c];
    if (rel < sm[c]) {
      float a = dec_f(vx[pos]), b = dec_f(vt[pos]);
      s += fabsf(a - b) * swt[c];
    }
  }
  red[tid] = s;
  __syncthreads();
  for (int st = 128; st > 0; st >>= 1) {
    if (tid < st) red[tid] += red[tid + st];
    __syncthreads();
  }
  if (tid == 0) atomicAdd(lossAcc, red[0]);
}

// ---------------- K9: final scalar
__global__ void k_final(const float* __restrict__ lossAcc, const float* __restrict__ loss_fil,
                        float* __restrict__ out)
{
  out[0] = *lossAcc + *loss_fil;
}

extern "C" void kernel_launch(void* const* d_in, const int* in_sizes, int n_in,
                              void* d_out, int out_size, void* d_ws, size_t ws_size,
                              hipStream_t stream)
{
  const float* x       = (const float*)d_in[0];
  const float* centers = (const float*)d_in[1];
  const float* ftarget = (const float*)d_in[2];
  const float* tgt     = (const float*)d_in[3];
  const int*   predT   = (const int*)d_in[4];
  float* out = (float*)d_out;

  char* ws = (char*)d_ws;
  float* fill_sum = (float*)(ws + 0);       // 16 f
  float* lossAcc  = (float*)(ws + 64);
  float* loss_fil = (float*)(ws + 68);
  int*   m_buf    = (int*)(ws + 128);
  float* w_buf    = (float*)(ws + 192);
  int*   p_buf    = (int*)(ws + 256);
  int*   pOff     = (int*)(ws + 320);       // 17 ints
  u32* histX = (u32*)(ws + 512);            // 512*16*4 = 32768
  u32* histT = (u32*)(ws + 512 + 32768);
  u32* baseX = (u32*)(ws + 512 + 65536);
  u32* baseT = (u32*)(ws + 512 + 98304);
  int* predX = (int*)(ws + 131584);         // 524288
  int* rankX = (int*)(ws + 655872);
  int* rankT = (int*)(ws + 1180160);
  u32* vbase = (u32*)(ws + VOFF);

  // dims per batch that fit workspace
  size_t avail_elems = (ws_size > VOFF) ? ((ws_size - VOFF) / 4) : 0;
  int Db = (int)(avail_elems / (2ull * SEG_STRIDE));
  if (Db > DIMS) Db = DIMS;
  if (Db < 1) Db = 1;

  hipMemsetAsync(ws, 0, 128, stream);
  k_assign<<<NBLK, 256, 0, stream>>>(x, centers, predT, predX, fill_sum, histX, histT);
  k_scan<<<1, 512, 0, stream>>>(histX, histT, baseX, baseT, fill_sum, ftarget,
                                m_buf, w_buf, p_buf, pOff, loss_fil);
  k_rank<<<NBLK, 256, 0, stream>>>(predX, predT, baseX, baseT, m_buf, rankX, rankT);

  for (int d0 = 0; d0 < DIMS; d0 += Db) {
    int Dbc = (Db < DIMS - d0) ? Db : (DIMS - d0);
    u32* valX = vbase;
    u32* valT = vbase + (size_t)Dbc * SEG_STRIDE;
    hipMemsetAsync(valX, 0xFF, 2ull * Dbc * SEG_STRIDE * 4ull, stream);
    k_scatter<<<NBLK, 256, 0, stream>>>(x, tgt, predX, predT, rankX, rankT, pOff,
                                        valX, valT, d0, Dbc);
    k_local_sort<<<dim3(32, 2 * Dbc), LST, 0, stream>>>(valX, valT, p_buf, pOff, Dbc);
    // fallback stages for segments > 16384 (early-exit when none)
    for (int kk = 2 * CHMAX; kk <= N_ROWS; kk <<= 1) {
      for (int j = kk >> 1; j >= CHMAX; j >>= 1)
        k_gpass<<<dim3(32, 2 * Dbc), 256, 0, stream>>>(valX, valT, p_buf, pOff, kk, j, Dbc);
      k_gfinish<<<dim3(16, 2 * Dbc), LST, 0, stream>>>(valX, valT, p_buf, pOff, kk, Dbc);
    }
    k_reduce<<<dim3(32, Dbc), 256, 0, stream>>>(valX, valT, pOff, m_buf, w_buf, lossAcc, Dbc);
  }
  k_final<<<1, 1, 0, stream>>>(lossAcc, loss_fil, out);
}

// Round 3
// 1508.617 us; speedup vs baseline: 1.0889x; 1.0309x over previous
//
#include <hip/hip_runtime.h>
#include <stdint.h>

#define N_ROWS 131072
#define DIMS 64
#define KCL 16
#define BETA 4.0f
#define NBLK 512            // N_ROWS / 256
#define CHMAX 16384         // max elements per LDS sort chunk (16384 * 4B = 64KB)
#define LST 1024
#define SEG_STRIDE 263168   // u32 elements per (dim,side): >= worst-case sum of padded cluster sizes
#define VOFF (1u<<21)

typedef unsigned long long u64;
typedef unsigned int u32;

__device__ __forceinline__ u32 enc_f(float f) {
  u32 u = __float_as_uint(f);
  return (u & 0x80000000u) ? ~u : (u | 0x80000000u);
}
__device__ __forceinline__ float dec_f(u32 e) {
  u32 u = (e & 0x80000000u) ? (e & 0x7FFFFFFFu) : ~e;
  return __uint_as_float(u);
}

// compare-swap: dd=true -> ascending (min at first arg)
#define CS(a,b,dd) { u32 _mn = min(a,b), _mx = max(a,b); a = (dd)?_mn:_mx; b = (dd)?_mx:_mn; }

// bitonic merge of 16 named regs, all comparators direction D (strides 8,4,2,1)
#define MERGE16(D) \
  CS(r0,r8,D)  CS(r1,r9,D)  CS(r2,r10,D) CS(r3,r11,D) CS(r4,r12,D) CS(r5,r13,D) CS(r6,r14,D) CS(r7,r15,D) \
  CS(r0,r4,D)  CS(r1,r5,D)  CS(r2,r6,D)  CS(r3,r7,D)  CS(r8,r12,D) CS(r9,r13,D) CS(r10,r14,D) CS(r11,r15,D) \
  CS(r0,r2,D)  CS(r1,r3,D)  CS(r4,r6,D)  CS(r5,r7,D)  CS(r8,r10,D) CS(r9,r11,D) CS(r12,r14,D) CS(r13,r15,D) \
  CS(r0,r1,D)  CS(r2,r3,D)  CS(r4,r5,D)  CS(r6,r7,D)  CS(r8,r9,D)  CS(r10,r11,D) CS(r12,r13,D) CS(r14,r15,D)

// full bitonic sort of 16 named regs with final direction D
#define SORT16(D) \
  CS(r0,r1,D)  CS(r2,r3,!(D))  CS(r4,r5,D)   CS(r6,r7,!(D))  CS(r8,r9,D)   CS(r10,r11,!(D)) CS(r12,r13,D)   CS(r14,r15,!(D)) \
  CS(r0,r2,D)  CS(r1,r3,D)     CS(r4,r6,!(D)) CS(r5,r7,!(D)) CS(r8,r10,D)  CS(r9,r11,D)     CS(r12,r14,!(D)) CS(r13,r15,!(D)) \
  CS(r0,r1,D)  CS(r2,r3,D)     CS(r4,r5,!(D)) CS(r6,r7,!(D)) CS(r8,r9,D)   CS(r10,r11,D)    CS(r12,r13,!(D)) CS(r14,r15,!(D)) \
  CS(r0,r4,D)  CS(r1,r5,D)     CS(r2,r6,D)   CS(r3,r7,D)    CS(r8,r12,!(D)) CS(r9,r13,!(D)) CS(r10,r14,!(D)) CS(r11,r15,!(D)) \
  CS(r0,r2,D)  CS(r1,r3,D)     CS(r4,r6,D)   CS(r5,r7,D)    CS(r8,r10,!(D)) CS(r9,r11,!(D)) CS(r12,r14,!(D)) CS(r13,r15,!(D)) \
  CS(r0,r1,D)  CS(r2,r3,D)     CS(r4,r5,D)   CS(r6,r7,D)    CS(r8,r9,!(D))  CS(r10,r11,!(D)) CS(r12,r13,!(D)) CS(r14,r15,!(D)) \
  MERGE16(D)

#define LDSLOAD16(arr) \
  r0=arr[(bas+0)^cc5];  r1=arr[(bas+1)^cc5];  r2=arr[(bas+2)^cc5];  r3=arr[(bas+3)^cc5]; \
  r4=arr[(bas+4)^cc5];  r5=arr[(bas+5)^cc5];  r6=arr[(bas+6)^cc5];  r7=arr[(bas+7)^cc5]; \
  r8=arr[(bas+8)^cc5];  r9=arr[(bas+9)^cc5];  r10=arr[(bas+10)^cc5]; r11=arr[(bas+11)^cc5]; \
  r12=arr[(bas+12)^cc5]; r13=arr[(bas+13)^cc5]; r14=arr[(bas+14)^cc5]; r15=arr[(bas+15)^cc5];

#define LDSSTORE16(arr) \
  arr[(bas+0)^cc5]=r0;  arr[(bas+1)^cc5]=r1;  arr[(bas+2)^cc5]=r2;  arr[(bas+3)^cc5]=r3; \
  arr[(bas+4)^cc5]=r4;  arr[(bas+5)^cc5]=r5;  arr[(bas+6)^cc5]=r6;  arr[(bas+7)^cc5]=r7; \
  arr[(bas+8)^cc5]=r8;  arr[(bas+9)^cc5]=r9;  arr[(bas+10)^cc5]=r10; arr[(bas+11)^cc5]=r11; \
  arr[(bas+12)^cc5]=r12; arr[(bas+13)^cc5]=r13; arr[(bas+14)^cc5]=r14; arr[(bas+15)^cc5]=r15;

// ---------------- K1: cluster assign + softmax filling + per-block histograms
__global__ __launch_bounds__(256) void k_assign(
    const float* __restrict__ x, const float* __restrict__ centers,
    const int* __restrict__ predT, int* __restrict__ predX,
    float* __restrict__ fill_sum, u32* __restrict__ histX, u32* __restrict__ histT)
{
  __shared__ float c[KCL][DIMS];
  __shared__ float cn[KCL];
  __shared__ float fs[KCL];
  __shared__ u32 hx[KCL], ht[KCL];
  int tid = threadIdx.x;
  for (int t = tid; t < KCL * DIMS; t += 256) c[t / DIMS][t % DIMS] = centers[t];
  if (tid < KCL) { fs[tid] = 0.f; hx[tid] = 0; ht[tid] = 0; }
  __syncthreads();
  if (tid < KCL) {
    float s = 0.f;
    for (int d = 0; d < DIMS; ++d) s += c[tid][d] * c[tid][d];
    cn[tid] = s;
  }
  __syncthreads();
  int i = blockIdx.x * 256 + tid;
  const float4* xr = (const float4*)(x + (size_t)i * DIMS);
  float dot[KCL];
#pragma unroll
  for (int k = 0; k < KCL; ++k) dot[k] = 0.f;
  for (int t = 0; t < DIMS / 4; ++t) {
    float4 v = xr[t];
#pragma unroll
    for (int k = 0; k < KCL; ++k)
      dot[k] += v.x * c[k][4 * t] + v.y * c[k][4 * t + 1] + v.z * c[k][4 * t + 2] + v.w * c[k][4 * t + 3];
  }
  float sc[KCL];
  float smin = 3.0e38f; int kmin = 0;
#pragma unroll
  for (int k = 0; k < KCL; ++k) {
    sc[k] = cn[k] - 2.f * dot[k];
    if (sc[k] < smin) { smin = sc[k]; kmin = k; }
  }
  float e[KCL]; float esum = 0.f;
#pragma unroll
  for (int k = 0; k < KCL; ++k) { e[k] = expf(-BETA * (sc[k] - smin)); esum += e[k]; }
  float inv = 1.f / esum;
#pragma unroll
  for (int k = 0; k < KCL; ++k) atomicAdd(&fs[k], e[k] * inv);
  predX[i] = kmin;
  atomicAdd(&hx[kmin], 1u);
  atomicAdd(&ht[predT[i]], 1u);
  __syncthreads();
  if (tid < KCL) {
    histX[blockIdx.x * KCL + tid] = hx[tid];
    histT[blockIdx.x * KCL + tid] = ht[tid];
    atomicAdd(&fill_sum[tid], fs[tid]);
  }
}

// ---------------- K2: scan hists -> bases, totals, m, w, p (pow2 pad), pOff, padOff, loss_fil
__global__ __launch_bounds__(512) void k_scan(
    const u32* __restrict__ histX, const u32* __restrict__ histT,
    u32* __restrict__ baseX, u32* __restrict__ baseT,
    const float* __restrict__ fill_sum, const float* __restrict__ ftarget,
    int* __restrict__ m_out, float* __restrict__ w_out,
    int* __restrict__ p_out, int* __restrict__ pOff_out, int* __restrict__ padOff_out,
    float* __restrict__ loss_fil)
{
  __shared__ u32 part[2][KCL][17];
  __shared__ u32 tot[2][KCL];
  __shared__ float sq[KCL];
  __shared__ int sp[KCL];
  __shared__ int smv[KCL];
  int tid = threadIdx.x;
  int side = tid >> 8;
  int rem = tid & 255;
  int c = rem >> 4;
  int sub = rem & 15;
  const u32* hist = side ? histT : histX;
  u32* base = side ? baseT : baseX;
  int b0 = sub * 32;
  u32 s = 0;
  for (int b = b0; b < b0 + 32; ++b) s += hist[b * KCL + c];
  part[side][c][sub] = s;
  __syncthreads();
  if (sub == 0) {
    u32 run = 0;
    for (int t = 0; t < 16; ++t) { u32 v = part[side][c][t]; part[side][c][t] = run; run += v; }
    tot[side][c] = run;
  }
  __syncthreads();
  u32 run = part[side][c][sub];
  for (int b = b0; b < b0 + 32; ++b) { base[b * KCL + c] = run; run += hist[b * KCL + c]; }
  if (tid < KCL) {
    int m = min((int)tot[0][tid], (int)tot[1][tid]);
    m_out[tid] = m;
    smv[tid] = m;
    w_out[tid] = (m > 0) ? 1.f / ((float)m * (float)DIMS) : 0.f;
    int pp = 32;
    while (pp < m) pp <<= 1;
    sp[tid] = pp;
    p_out[tid] = pp;
    float d = fill_sum[tid] / (float)N_ROWS - ftarget[tid];
    sq[tid] = d * d;
  }
  __syncthreads();
  if (tid == 0) {
    float s2 = 0.f;
    int acc = 0, pacc = 0;
    for (int k = 0; k < KCL; ++k) {
      s2 += sq[k];
      pOff_out[k] = acc;
      acc += sp[k];
      padOff_out[k] = pacc;
      pacc += sp[k] - smv[k];
    }
    pOff_out[KCL] = acc;
    padOff_out[KCL] = pacc;
    *loss_fil = s2 / (float)KCL;
  }
}

// ---------------- K3: ordered within-cluster rank (-1 if not kept)
__global__ __launch_bounds__(256) void k_rank(
    const int* __restrict__ predX, const int* __restrict__ predT,
    const u32* __restrict__ baseX, const u32* __restrict__ baseT,
    const int* __restrict__ m, int* __restrict__ rankX, int* __restrict__ rankT)
{
  __shared__ int wcX[4][KCL], wcT[4][KCL];
  int tid = threadIdx.x;
  int lane = tid & 63, wave = tid >> 6;
  int i = blockIdx.x * 256 + tid;
  int kx = predX[i], kt = predT[i];
  u64 below = (1ull << lane) - 1ull;
  int lrX = 0, lrT = 0;
  for (int cc = 0; cc < KCL; ++cc) {
    u64 mx = __ballot(kx == cc);
    u64 mt = __ballot(kt == cc);
    if (kx == cc) lrX = __popcll(mx & below);
    if (kt == cc) lrT = __popcll(mt & below);
    if (lane == 0) { wcX[wave][cc] = __popcll(mx); wcT[wave][cc] = __popcll(mt); }
  }
  __syncthreads();
  int wbX = 0, wbT = 0;
  for (int w2 = 0; w2 < wave; ++w2) { wbX += wcX[w2][kx]; wbT += wcT[w2][kt]; }
  int rX = (int)baseX[blockIdx.x * KCL + kx] + wbX + lrX;
  int rT = (int)baseT[blockIdx.x * KCL + kt] + wbT + lrT;
  rankX[i] = (rX < m[kx]) ? rX : -1;
  rankT[i] = (rT < m[kt]) ? rT : -1;
}

// ---------------- K3b: write 0xFF pads only into [pOff+m, pOff+p) per segment
__global__ __launch_bounds__(256) void k_pad(
    u32* __restrict__ vbase, const int* __restrict__ pOffG,
    const int* __restrict__ padOffG, const int* __restrict__ mG)
{
  __shared__ int sOff[KCL];
  __shared__ int sPad[KCL + 1];
  __shared__ int sM[KCL];
  int tid = threadIdx.x;
  if (tid < KCL) { sOff[tid] = pOffG[tid]; sM[tid] = mG[tid]; }
  if (tid <= KCL) sPad[tid] = padOffG[tid];
  __syncthreads();
  int tot = sPad[KCL];
  u32* seg = vbase + (size_t)blockIdx.y * SEG_STRIDE;
  for (int tt = blockIdx.x * 256 + tid; tt < tot; tt += gridDim.x * 256) {
    int c = 0;
#pragma unroll
    for (int cc = 1; cc < KCL; ++cc) c += (tt >= sPad[cc]) ? 1 : 0;
    seg[sOff[c] + sM[c] + (tt - sPad[c])] = 0xFFFFFFFFu;
  }
}

// ---------------- K4: scatter kept encoded values into cluster-partitioned dim arrays
__global__ __launch_bounds__(256) void k_scatter(
    const float* __restrict__ x, const float* __restrict__ tgt,
    const int* __restrict__ predX, const int* __restrict__ predT,
    const int* __restrict__ rankX, const int* __restrict__ rankT,
    const int* __restrict__ pOffG,
    u32* __restrict__ valX, u32* __restrict__ valT, int d0, int Dbc)
{
  __shared__ int spOff[KCL + 1];
  int tid = threadIdx.x;
  if (tid <= KCL) spOff[tid] = pOffG[tid];
  __syncthreads();
  int i = blockIdx.x * 256 + tid;
  int cx = predX[i], rx = rankX[i];
  int ct = predT[i], rt = rankT[i];
  bool vec = ((Dbc & 3) == 0);
  if (rx >= 0) {
    size_t pos = (size_t)spOff[cx] + rx;
    const float* xr = x + (size_t)i * DIMS + d0;
    if (vec) {
      const float4* x4 = (const float4*)xr;
      for (int d = 0; d < Dbc; d += 4) {
        float4 v = x4[d >> 2];
        valX[(size_t)(d + 0) * SEG_STRIDE + pos] = enc_f(v.x);
        valX[(size_t)(d + 1) * SEG_STRIDE + pos] = enc_f(v.y);
        valX[(size_t)(d + 2) * SEG_STRIDE + pos] = enc_f(v.z);
        valX[(size_t)(d + 3) * SEG_STRIDE + pos] = enc_f(v.w);
      }
    } else {
      for (int d = 0; d < Dbc; ++d) valX[(size_t)d * SEG_STRIDE + pos] = enc_f(xr[d]);
    }
  }
  if (rt >= 0) {
    size_t pos = (size_t)spOff[ct] + rt;
    const float* tr = tgt + (size_t)i * DIMS + d0;
    if (vec) {
      const float4* t4 = (const float4*)tr;
      for (int d = 0; d < Dbc; d += 4) {
        float4 v = t4[d >> 2];
        valT[(size_t)(d + 0) * SEG_STRIDE + pos] = enc_f(v.x);
        valT[(size_t)(d + 1) * SEG_STRIDE + pos] = enc_f(v.y);
        valT[(size_t)(d + 2) * SEG_STRIDE + pos] = enc_f(v.z);
        valT[(size_t)(d + 3) * SEG_STRIDE + pos] = enc_f(v.w);
      }
    } else {
      for (int d = 0; d < Dbc; ++d) valT[(size_t)d * SEG_STRIDE + pos] = enc_f(tr[d]);
    }
  }
}

// ---------------- K5: per-segment sort; reg tile of 16 named scalars + swizzled LDS passes
__global__ __launch_bounds__(LST) void k_local_sort(
    u32* __restrict__ vbase, const int* __restrict__ pG, const int* __restrict__ pOffG)
{
  __shared__ u32 lds[CHMAX];
  int t = blockIdx.x, c = -1, sub = 0, acc = 0;
  for (int cc = 0; cc < KCL; ++cc) {
    int pc0 = pG[cc];
    int nc = (pc0 > CHMAX) ? (pc0 / CHMAX) : 1;
    if (t < acc + nc) { c = cc; sub = t - acc; break; }
    acc += nc;
  }
  if (c < 0) return;
  int pc = pG[c];
  u32 CH = (u32)min(pc, CHMAX);
  u32 gb = (u32)sub * (u32)CHMAX;
  u32* seg = vbase + (size_t)blockIdx.y * SEG_STRIDE + pOffG[c] + gb;
  u32 tid = threadIdx.x;
  u32 bas = tid << 4;
  bool act = (bas < CH);
  u32 cc5 = (tid >> 1) & 31u;
  u32 r0,r1,r2,r3,r4,r5,r6,r7,r8,r9,r10,r11,r12,r13,r14,r15;

  if (act) {
    const uint4* sp4 = (const uint4*)(seg + bas);
    uint4 a0 = sp4[0], a1 = sp4[1], a2 = sp4[2], a3 = sp4[3];
    r0=a0.x; r1=a0.y; r2=a0.z; r3=a0.w;
    r4=a1.x; r5=a1.y; r6=a1.z; r7=a1.w;
    r8=a2.x; r9=a2.y; r10=a2.z; r11=a2.w;
    r12=a3.x; r13=a3.y; r14=a3.z; r15=a3.w;
    bool D = (((gb + bas) & 16u) == 0u);
    SORT16(D);
    LDSSTORE16(lds);
  }
  __syncthreads();

  for (u32 k = 32; k <= CH; k <<= 1) {
    for (u32 j = k >> 1; j >= 16; j >>= 1) {
      for (u32 tt = tid; tt < (CH >> 1); tt += LST) {
        u32 i = ((tt & ~(j - 1)) << 1) | (tt & (j - 1));
        u32 l = i | j;
        bool up = (((gb + i) & k) == 0);
        u32 ei = i ^ ((i >> 5) & 31u);
        u32 el = l ^ ((l >> 5) & 31u);
        u32 A = lds[ei], Bv = lds[el];
        u32 mn = min(A, Bv), mx = max(A, Bv);
        lds[ei] = up ? mn : mx;
        lds[el] = up ? mx : mn;
      }
      __syncthreads();
    }
    if (act) {
      LDSLOAD16(lds);
      bool D = (((gb + bas) & k) == 0);
      MERGE16(D);
      if (k < CH) {
        LDSSTORE16(lds);
      } else {
        uint4* op4 = (uint4*)(seg + bas);
        op4[0] = make_uint4(r0, r1, r2, r3);
        op4[1] = make_uint4(r4, r5, r6, r7);
        op4[2] = make_uint4(r8, r9, r10, r11);
        op4[3] = make_uint4(r12, r13, r14, r15);
      }
    }
    __syncthreads();
  }
}

// ---------------- K6: global bitonic pass for big segments (early-exit fallback)
__global__ __launch_bounds__(256) void k_gpass(
    u32* __restrict__ vbase, const int* __restrict__ pG, const int* __restrict__ pOffG,
    int kk, int j)
{
  u32* base = vbase + (size_t)blockIdx.y * SEG_STRIDE;
  int pb[KCL]; int tot = 0;
#pragma unroll
  for (int c = 0; c < KCL; ++c) {
    pb[c] = tot;
    int pc = pG[c];
    if (pc >= kk) tot += pc >> 1;
  }
  for (int g = blockIdx.x * 256 + threadIdx.x; g < tot; g += gridDim.x * 256) {
    int c = 0;
#pragma unroll
    for (int cc = 1; cc < KCL; ++cc) c += (g >= pb[cc]) ? 1 : 0;
    int u = g - pb[c];
    int i = ((u & ~(j - 1)) << 1) | (u & (j - 1));
    int l = i | j;
    bool up = ((i & kk) == 0);
    u32* s2 = base + pOffG[c];
    u32 A = s2[i], Bv = s2[l];
    if ((A > Bv) == up) { s2[i] = Bv; s2[l] = A; }
  }
}

// ---------------- K7: finish a big-segment stage (strides <=8192) in LDS (fallback)
__global__ __launch_bounds__(LST) void k_gfinish(
    u32* __restrict__ vbase, const int* __restrict__ pG, const int* __restrict__ pOffG, int kk)
{
  __shared__ u32 lds[CHMAX];
  int t = blockIdx.x, c = -1, sub = 0, acc = 0;
  for (int cc = 0; cc < KCL; ++cc) {
    int pc = pG[cc];
    if (pc < kk) continue;
    int nc = pc / CHMAX;
    if (t < acc + nc) { c = cc; sub = t - acc; break; }
    acc += nc;
  }
  if (c < 0) return;
  u32 gb = (u32)sub * (u32)CHMAX;
  bool up = ((gb & (u32)kk) == 0);
  u32* seg = vbase + (size_t)blockIdx.y * SEG_STRIDE + pOffG[c] + gb;
  u32 tid = threadIdx.x;
  for (u32 e = tid; e < CHMAX; e += LST) lds[e ^ ((e >> 5) & 31u)] = seg[e];
  __syncthreads();
  for (u32 j = CHMAX >> 1; j >= 1; j >>= 1) {
    for (u32 tt = tid; tt < (CHMAX >> 1); tt += LST) {
      u32 i = ((tt & ~(j - 1)) << 1) | (tt & (j - 1));
      u32 l = i | j;
      u32 ei = i ^ ((i >> 5) & 31u);
      u32 el = l ^ ((l >> 5) & 31u);
      u32 A = lds[ei], Bv = lds[el];
      u32 mn = min(A, Bv), mx = max(A, Bv);
      lds[ei] = up ? mn : mx;
      lds[el] = up ? mx : mn;
    }
    __syncthreads();
  }
  for (u32 e = tid; e < CHMAX; e += LST) seg[e] = lds[e ^ ((e >> 5) & 31u)];
}

// ---------------- K8: pair sorted X/T per (cluster,dim), weighted |diff| reduce
__global__ __launch_bounds__(256) void k_reduce(
    const u32* __restrict__ valX, const u32* __restrict__ valT,
    const int* __restrict__ pOffG, const int* __restrict__ mG,
    const float* __restrict__ wG, float* __restrict__ lossAcc, int Dbc)
{
  __shared__ int spOff[KCL + 1];
  __shared__ int sm[KCL];
  __shared__ float swt[KCL];
  __shared__ float red[256];
  int tid = threadIdx.x;
  if (tid <= KCL) spOff[tid] = pOffG[tid];
  if (tid < KCL) { sm[tid] = mG[tid]; swt[tid] = wG[tid]; }
  __syncthreads();
  int d = blockIdx.y;
  const u32* vx = valX + (size_t)d * SEG_STRIDE;
  const u32* vt = valT + (size_t)d * SEG_STRIDE;
  int P16 = spOff[KCL];
  float s = 0.f;
  for (int pos = blockIdx.x * 256 + tid; pos < P16; pos += gridDim.x * 256) {
    int c = 0;
#pragma unroll
    for (int cc = 1; cc < KCL; ++cc) c += (pos >= spOff[cc]) ? 1 : 0;
    int rel = pos - spOff[c];
    if (rel < sm[c]) {
      float a = dec_f(vx[pos]), b = dec_f(vt[pos]);
      s += fabsf(a - b) * swt[c];
    }
  }
  red[tid] = s;
  __syncthreads();
  for (int st = 128; st > 0; st >>= 1) {
    if (tid < st) red[tid] += red[tid + st];
    __syncthreads();
  }
  if (tid == 0) atomicAdd(lossAcc, red[0]);
}

// ---------------- K9: final scalar
__global__ void k_final(const float* __restrict__ lossAcc, const float* __restrict__ loss_fil,
                        float* __restrict__ out)
{
  out[0] = *lossAcc + *loss_fil;
}

extern "C" void kernel_launch(void* const* d_in, const int* in_sizes, int n_in,
                              void* d_out, int out_size, void* d_ws, size_t ws_size,
                              hipStream_t stream)
{
  const float* x       = (const float*)d_in[0];
  const float* centers = (const float*)d_in[1];
  const float* ftarget = (const float*)d_in[2];
  const float* tgt     = (const float*)d_in[3];
  const int*   predT   = (const int*)d_in[4];
  float* out = (float*)d_out;

  char* ws = (char*)d_ws;
  float* fill_sum = (float*)(ws + 0);       // 16 f (zeroed)
  float* lossAcc  = (float*)(ws + 64);      // zeroed
  float* loss_fil = (float*)(ws + 68);      // zeroed
  int*   m_buf    = (int*)(ws + 128);
  float* w_buf    = (float*)(ws + 192);
  int*   p_buf    = (int*)(ws + 256);
  int*   pOff     = (int*)(ws + 320);       // 17 ints
  int*   padOff   = (int*)(ws + 400);       // 17 ints
  u32* histX = (u32*)(ws + 512);            // 512*16*4 = 32768
  u32* histT = (u32*)(ws + 512 + 32768);
  u32* baseX = (u32*)(ws + 512 + 65536);
  u32* baseT = (u32*)(ws + 512 + 98304);
  int* predX = (int*)(ws + 131584);         // 524288
  int* rankX = (int*)(ws + 655872);
  int* rankT = (int*)(ws + 1180160);
  u32* vbase = (u32*)(ws + VOFF);

  size_t avail_elems = (ws_size > VOFF) ? ((ws_size - VOFF) / 4) : 0;
  int Db = (int)(avail_elems / (2ull * SEG_STRIDE));
  if (Db > DIMS) Db = DIMS;
  if (Db >= 4) Db &= ~3;
  if (Db < 1) Db = 1;

  hipMemsetAsync(ws, 0, 128, stream);
  k_assign<<<NBLK, 256, 0, stream>>>(x, centers, predT, predX, fill_sum, histX, histT);
  k_scan<<<1, 512, 0, stream>>>(histX, histT, baseX, baseT, fill_sum, ftarget,
                                m_buf, w_buf, p_buf, pOff, padOff, loss_fil);
  k_rank<<<NBLK, 256, 0, stream>>>(predX, predT, baseX, baseT, m_buf, rankX, rankT);

  for (int d0 = 0; d0 < DIMS; d0 += Db) {
    int Dbc = (Db < DIMS - d0) ? Db : (DIMS - d0);
    u32* valX = vbase;
    u32* valT = vbase + (size_t)Dbc * SEG_STRIDE;
    k_pad<<<dim3(16, 2 * Dbc), 256, 0, stream>>>(vbase, pOff, padOff, m_buf);
    k_scatter<<<NBLK, 256, 0, stream>>>(x, tgt, predX, predT, rankX, rankT, pOff,
                                        valX, valT, d0, Dbc);
    k_local_sort<<<dim3(32, 2 * Dbc), LST, 0, stream>>>(vbase, p_buf, pOff);
    // fallback stages for segments > 16384 (early-exit when none)
    for (int kk = 2 * CHMAX; kk <= N_ROWS; kk <<= 1) {
      for (int j = kk >> 1; j >= CHMAX; j >>= 1)
        k_gpass<<<dim3(16, 2 * Dbc), 256, 0, stream>>>(vbase, p_buf, pOff, kk, j);
      k_gfinish<<<dim3(8, 2 * Dbc), LST, 0, stream>>>(vbase, p_buf, pOff, kk);
    }
    k_reduce<<<dim3(32, Dbc), 256, 0, stream>>>(valX, valT, pOff, m_buf, w_buf, lossAcc, Dbc);
  }
  k_final<<<1, 1, 0, stream>>>(lossAcc, loss_fil, out);
}

// Round 5
// 1127.442 us; speedup vs baseline: 1.4571x; 1.3381x over previous
//
#include <hip/hip_runtime.h>
#include <stdint.h>

#define N_ROWS 131072
#define DIMS 64
#define KCL 16
#define BETA 4.0f
#define NBLK 512            // N_ROWS / 256
#define CHUNK4 4096         // elements per LDS sort chunk (4096 * 4B = 16KB LDS)
#define SEG_STRIDE 263168   // u32 elements per (dim,side): >= worst-case sum of padded cluster sizes
#define VOFF (1u<<21)

typedef unsigned long long u64;
typedef unsigned int u32;

__device__ __forceinline__ u32 enc_f(float f) {
  u32 u = __float_as_uint(f);
  return (u & 0x80000000u) ? ~u : (u | 0x80000000u);
}
__device__ __forceinline__ float dec_f(u32 e) {
  u32 u = (e & 0x80000000u) ? (e & 0x7FFFFFFFu) : ~e;
  return __uint_as_float(u);
}

// compare-swap: dd=true -> ascending (min at first arg)
#define CS(a,b,dd) { u32 _mn = min(a,b), _mx = max(a,b); a = (dd)?_mn:_mx; b = (dd)?_mx:_mn; }

// bitonic merge of 16 named regs, all comparators direction D (strides 8,4,2,1)
#define MERGE16(D) \
  CS(r0,r8,D)  CS(r1,r9,D)  CS(r2,r10,D) CS(r3,r11,D) CS(r4,r12,D) CS(r5,r13,D) CS(r6,r14,D) CS(r7,r15,D) \
  CS(r0,r4,D)  CS(r1,r5,D)  CS(r2,r6,D)  CS(r3,r7,D)  CS(r8,r12,D) CS(r9,r13,D) CS(r10,r14,D) CS(r11,r15,D) \
  CS(r0,r2,D)  CS(r1,r3,D)  CS(r4,r6,D)  CS(r5,r7,D)  CS(r8,r10,D) CS(r9,r11,D) CS(r12,r14,D) CS(r13,r15,D) \
  CS(r0,r1,D)  CS(r2,r3,D)  CS(r4,r5,D)  CS(r6,r7,D)  CS(r8,r9,D)  CS(r10,r11,D) CS(r12,r13,D) CS(r14,r15,D)

// full bitonic sort of 16 named regs with final direction D
#define SORT16(D) \
  CS(r0,r1,D)  CS(r2,r3,!(D))  CS(r4,r5,D)   CS(r6,r7,!(D))  CS(r8,r9,D)   CS(r10,r11,!(D)) CS(r12,r13,D)   CS(r14,r15,!(D)) \
  CS(r0,r2,D)  CS(r1,r3,D)     CS(r4,r6,!(D)) CS(r5,r7,!(D)) CS(r8,r10,D)  CS(r9,r11,D)     CS(r12,r14,!(D)) CS(r13,r15,!(D)) \
  CS(r0,r1,D)  CS(r2,r3,D)     CS(r4,r5,!(D)) CS(r6,r7,!(D)) CS(r8,r9,D)   CS(r10,r11,D)    CS(r12,r13,!(D)) CS(r14,r15,!(D)) \
  CS(r0,r4,D)  CS(r1,r5,D)     CS(r2,r6,D)   CS(r3,r7,D)    CS(r8,r12,!(D)) CS(r9,r13,!(D)) CS(r10,r14,!(D)) CS(r11,r15,!(D)) \
  CS(r0,r2,D)  CS(r1,r3,D)     CS(r4,r6,D)   CS(r5,r7,D)    CS(r8,r10,!(D)) CS(r9,r11,!(D)) CS(r12,r14,!(D)) CS(r13,r15,!(D)) \
  CS(r0,r1,D)  CS(r2,r3,D)     CS(r4,r5,D)   CS(r6,r7,D)    CS(r8,r9,!(D))  CS(r10,r11,!(D)) CS(r12,r13,!(D)) CS(r14,r15,!(D)) \
  MERGE16(D)

#define REGS_FROM4(a0,a1,a2,a3) \
  r0=a0.x; r1=a0.y; r2=a0.z; r3=a0.w; r4=a1.x; r5=a1.y; r6=a1.z; r7=a1.w; \
  r8=a2.x; r9=a2.y; r10=a2.z; r11=a2.w; r12=a3.x; r13=a3.y; r14=a3.z; r15=a3.w;

// ---------------- K1: cluster assign + softmax filling + per-block histograms
__global__ __launch_bounds__(256) void k_assign(
    const float* __restrict__ x, const float* __restrict__ centers,
    const int* __restrict__ predT, int* __restrict__ predX,
    float* __restrict__ fill_sum, u32* __restrict__ histX, u32* __restrict__ histT)
{
  __shared__ float c[KCL][DIMS];
  __shared__ float cn[KCL];
  __shared__ float fs[KCL];
  __shared__ u32 hx[KCL], ht[KCL];
  int tid = threadIdx.x;
  for (int t = tid; t < KCL * DIMS; t += 256) c[t / DIMS][t % DIMS] = centers[t];
  if (tid < KCL) { fs[tid] = 0.f; hx[tid] = 0; ht[tid] = 0; }
  __syncthreads();
  if (tid < KCL) {
    float s = 0.f;
    for (int d = 0; d < DIMS; ++d) s += c[tid][d] * c[tid][d];
    cn[tid] = s;
  }
  __syncthreads();
  int i = blockIdx.x * 256 + tid;
  const float4* xr = (const float4*)(x + (size_t)i * DIMS);
  float dot[KCL];
#pragma unroll
  for (int k = 0; k < KCL; ++k) dot[k] = 0.f;
  for (int t = 0; t < DIMS / 4; ++t) {
    float4 v = xr[t];
#pragma unroll
    for (int k = 0; k < KCL; ++k)
      dot[k] += v.x * c[k][4 * t] + v.y * c[k][4 * t + 1] + v.z * c[k][4 * t + 2] + v.w * c[k][4 * t + 3];
  }
  float sc[KCL];
  float smin = 3.0e38f; int kmin = 0;
#pragma unroll
  for (int k = 0; k < KCL; ++k) {
    sc[k] = cn[k] - 2.f * dot[k];
    if (sc[k] < smin) { smin = sc[k]; kmin = k; }
  }
  float e[KCL]; float esum = 0.f;
#pragma unroll
  for (int k = 0; k < KCL; ++k) { e[k] = expf(-BETA * (sc[k] - smin)); esum += e[k]; }
  float inv = 1.f / esum;
#pragma unroll
  for (int k = 0; k < KCL; ++k) atomicAdd(&fs[k], e[k] * inv);
  predX[i] = kmin;
  atomicAdd(&hx[kmin], 1u);
  atomicAdd(&ht[predT[i]], 1u);
  __syncthreads();
  if (tid < KCL) {
    histX[blockIdx.x * KCL + tid] = hx[tid];
    histT[blockIdx.x * KCL + tid] = ht[tid];
    atomicAdd(&fill_sum[tid], fs[tid]);
  }
}

// ---------------- K2: scan hists -> bases, totals, m, w, p (pow2 pad), pOff, padOff, loss_fil
__global__ __launch_bounds__(512) void k_scan(
    const u32* __restrict__ histX, const u32* __restrict__ histT,
    u32* __restrict__ baseX, u32* __restrict__ baseT,
    const float* __restrict__ fill_sum, const float* __restrict__ ftarget,
    int* __restrict__ m_out, float* __restrict__ w_out,
    int* __restrict__ p_out, int* __restrict__ pOff_out, int* __restrict__ padOff_out,
    float* __restrict__ loss_fil)
{
  __shared__ u32 part[2][KCL][17];
  __shared__ u32 tot[2][KCL];
  __shared__ float sq[KCL];
  __shared__ int sp[KCL];
  __shared__ int smv[KCL];
  int tid = threadIdx.x;
  int side = tid >> 8;
  int rem = tid & 255;
  int c = rem >> 4;
  int sub = rem & 15;
  const u32* hist = side ? histT : histX;
  u32* base = side ? baseT : baseX;
  int b0 = sub * 32;
  u32 s = 0;
  for (int b = b0; b < b0 + 32; ++b) s += hist[b * KCL + c];
  part[side][c][sub] = s;
  __syncthreads();
  if (sub == 0) {
    u32 run = 0;
    for (int t = 0; t < 16; ++t) { u32 v = part[side][c][t]; part[side][c][t] = run; run += v; }
    tot[side][c] = run;
  }
  __syncthreads();
  u32 run = part[side][c][sub];
  for (int b = b0; b < b0 + 32; ++b) { base[b * KCL + c] = run; run += hist[b * KCL + c]; }
  if (tid < KCL) {
    int m = min((int)tot[0][tid], (int)tot[1][tid]);
    m_out[tid] = m;
    smv[tid] = m;
    w_out[tid] = (m > 0) ? 1.f / ((float)m * (float)DIMS) : 0.f;
    int pp = 32;
    while (pp < m) pp <<= 1;
    sp[tid] = pp;
    p_out[tid] = pp;
    float d = fill_sum[tid] / (float)N_ROWS - ftarget[tid];
    sq[tid] = d * d;
  }
  __syncthreads();
  if (tid == 0) {
    float s2 = 0.f;
    int acc = 0, pacc = 0;
    for (int k = 0; k < KCL; ++k) {
      s2 += sq[k];
      pOff_out[k] = acc;
      acc += sp[k];
      padOff_out[k] = pacc;
      pacc += sp[k] - smv[k];
    }
    pOff_out[KCL] = acc;
    padOff_out[KCL] = pacc;
    *loss_fil = s2 / (float)KCL;
  }
}

// ---------------- K3: ordered within-cluster rank (-1 if not kept)
__global__ __launch_bounds__(256) void k_rank(
    const int* __restrict__ predX, const int* __restrict__ predT,
    const u32* __restrict__ baseX, const u32* __restrict__ baseT,
    const int* __restrict__ m, int* __restrict__ rankX, int* __restrict__ rankT)
{
  __shared__ int wcX[4][KCL], wcT[4][KCL];
  int tid = threadIdx.x;
  int lane = tid & 63, wave = tid >> 6;
  int i = blockIdx.x * 256 + tid;
  int kx = predX[i], kt = predT[i];
  u64 below = (1ull << lane) - 1ull;
  int lrX = 0, lrT = 0;
  for (int cc = 0; cc < KCL; ++cc) {
    u64 mx = __ballot(kx == cc);
    u64 mt = __ballot(kt == cc);
    if (kx == cc) lrX = __popcll(mx & below);
    if (kt == cc) lrT = __popcll(mt & below);
    if (lane == 0) { wcX[wave][cc] = __popcll(mx); wcT[wave][cc] = __popcll(mt); }
  }
  __syncthreads();
  int wbX = 0, wbT = 0;
  for (int w2 = 0; w2 < wave; ++w2) { wbX += wcX[w2][kx]; wbT += wcT[w2][kt]; }
  int rX = (int)baseX[blockIdx.x * KCL + kx] + wbX + lrX;
  int rT = (int)baseT[blockIdx.x * KCL + kt] + wbT + lrT;
  rankX[i] = (rX < m[kx]) ? rX : -1;
  rankT[i] = (rT < m[kt]) ? rT : -1;
}

// ---------------- K3b: write 0xFF pads only into [pOff+m, pOff+p) per segment
__global__ __launch_bounds__(256) void k_pad(
    u32* __restrict__ vbase, const int* __restrict__ pOffG,
    const int* __restrict__ padOffG, const int* __restrict__ mG)
{
  __shared__ int sOff[KCL];
  __shared__ int sPad[KCL + 1];
  __shared__ int sM[KCL];
  int tid = threadIdx.x;
  if (tid < KCL) { sOff[tid] = pOffG[tid]; sM[tid] = mG[tid]; }
  if (tid <= KCL) sPad[tid] = padOffG[tid];
  __syncthreads();
  int tot = sPad[KCL];
  u32* seg = vbase + (size_t)blockIdx.y * SEG_STRIDE;
  for (int tt = blockIdx.x * 256 + tid; tt < tot; tt += gridDim.x * 256) {
    int c = 0;
#pragma unroll
    for (int cc = 1; cc < KCL; ++cc) c += (tt >= sPad[cc]) ? 1 : 0;
    seg[sOff[c] + sM[c] + (tt - sPad[c])] = 0xFFFFFFFFu;
  }
}

// ---------------- K4: scatter kept encoded values into cluster-partitioned dim arrays
__global__ __launch_bounds__(256) void k_scatter(
    const float* __restrict__ x, const float* __restrict__ tgt,
    const int* __restrict__ predX, const int* __restrict__ predT,
    const int* __restrict__ rankX, const int* __restrict__ rankT,
    const int* __restrict__ pOffG,
    u32* __restrict__ valX, u32* __restrict__ valT, int d0, int Dbc)
{
  __shared__ int spOff[KCL + 1];
  int tid = threadIdx.x;
  if (tid <= KCL) spOff[tid] = pOffG[tid];
  __syncthreads();
  int i = blockIdx.x * 256 + tid;
  int cx = predX[i], rx = rankX[i];
  int ct = predT[i], rt = rankT[i];
  bool vec = ((Dbc & 3) == 0);
  if (rx >= 0) {
    size_t pos = (size_t)spOff[cx] + rx;
    const float* xr = x + (size_t)i * DIMS + d0;
    if (vec) {
      const float4* x4 = (const float4*)xr;
      for (int d = 0; d < Dbc; d += 4) {
        float4 v = x4[d >> 2];
        valX[(size_t)(d + 0) * SEG_STRIDE + pos] = enc_f(v.x);
        valX[(size_t)(d + 1) * SEG_STRIDE + pos] = enc_f(v.y);
        valX[(size_t)(d + 2) * SEG_STRIDE + pos] = enc_f(v.z);
        valX[(size_t)(d + 3) * SEG_STRIDE + pos] = enc_f(v.w);
      }
    } else {
      for (int d = 0; d < Dbc; ++d) valX[(size_t)d * SEG_STRIDE + pos] = enc_f(xr[d]);
    }
  }
  if (rt >= 0) {
    size_t pos = (size_t)spOff[ct] + rt;
    const float* tr = tgt + (size_t)i * DIMS + d0;
    if (vec) {
      const float4* t4 = (const float4*)tr;
      for (int d = 0; d < Dbc; d += 4) {
        float4 v = t4[d >> 2];
        valT[(size_t)(d + 0) * SEG_STRIDE + pos] = enc_f(v.x);
        valT[(size_t)(d + 1) * SEG_STRIDE + pos] = enc_f(v.y);
        valT[(size_t)(d + 2) * SEG_STRIDE + pos] = enc_f(v.z);
        valT[(size_t)(d + 3) * SEG_STRIDE + pos] = enc_f(v.w);
      }
    } else {
      for (int d = 0; d < Dbc; ++d) valT[(size_t)d * SEG_STRIDE + pos] = enc_f(tr[d]);
    }
  }
}

// ---------------- K5: per-chunk LDS bitonic sort; 256 thr, 16/thread regs, b128 LDS
__global__ __launch_bounds__(256, 8) void k_local_sort(
    u32* __restrict__ vbase, const int* __restrict__ pG, const int* __restrict__ pOffG)
{
  __shared__ __align__(16) u32 lds[CHUNK4];
  int t = blockIdx.x, c = -1, sub = 0, acc = 0;
  for (int cc = 0; cc < KCL; ++cc) {
    int pc0 = pG[cc];
    int nc = (pc0 > CHUNK4) ? (pc0 / CHUNK4) : 1;
    if (t < acc + nc) { c = cc; sub = t - acc; break; }
    acc += nc;
  }
  if (c < 0) return;
  int pc = pG[c];
  u32 CH = (u32)min(pc, CHUNK4);
  u32 gb = (u32)sub * (u32)CHUNK4;
  u32* seg = vbase + (size_t)blockIdx.y * SEG_STRIDE + pOffG[c] + gb;
  u32 tid = threadIdx.x;
  u32 bas = tid << 4;
  bool act = (bas < CH);
  u32 r0,r1,r2,r3,r4,r5,r6,r7,r8,r9,r10,r11,r12,r13,r14,r15;

  if (act) {
    const uint4* sp4 = (const uint4*)(seg + bas);
    uint4 a0 = sp4[0], a1 = sp4[1], a2 = sp4[2], a3 = sp4[3];
    REGS_FROM4(a0, a1, a2, a3);
    bool D = (((gb + bas) & 16u) == 0u);
    SORT16(D);
    uint4* l4 = (uint4*)&lds[bas];
    l4[0] = make_uint4(r0,r1,r2,r3);   l4[1] = make_uint4(r4,r5,r6,r7);
    l4[2] = make_uint4(r8,r9,r10,r11); l4[3] = make_uint4(r12,r13,r14,r15);
  }
  __syncthreads();

  for (u32 k = 32; k <= CH; k <<= 1) {
    for (u32 j = k >> 1; j >= 16; j >>= 1) {
      for (u32 p4 = tid << 2; p4 < (CH >> 1); p4 += 256 * 4) {
        u32 i = ((p4 & ~(j - 1)) << 1) | (p4 & (j - 1));
        bool up = (((gb + i) & k) == 0);
        uint4 A = *(const uint4*)&lds[i];
        uint4 B = *(const uint4*)&lds[i + j];
        CS(A.x, B.x, up) CS(A.y, B.y, up) CS(A.z, B.z, up) CS(A.w, B.w, up)
        *(uint4*)&lds[i] = A;
        *(uint4*)&lds[i + j] = B;
      }
      __syncthreads();
    }
    if (act) {
      const uint4* l4 = (const uint4*)&lds[bas];
      uint4 a0 = l4[0], a1 = l4[1], a2 = l4[2], a3 = l4[3];
      REGS_FROM4(a0, a1, a2, a3);
      bool D = (((gb + bas) & k) == 0);
      MERGE16(D);
      if (k < CH) {
        uint4* s4 = (uint4*)&lds[bas];
        s4[0] = make_uint4(r0,r1,r2,r3);   s4[1] = make_uint4(r4,r5,r6,r7);
        s4[2] = make_uint4(r8,r9,r10,r11); s4[3] = make_uint4(r12,r13,r14,r15);
      } else {
        uint4* o4 = (uint4*)(seg + bas);
        o4[0] = make_uint4(r0,r1,r2,r3);   o4[1] = make_uint4(r4,r5,r6,r7);
        o4[2] = make_uint4(r8,r9,r10,r11); o4[3] = make_uint4(r12,r13,r14,r15);
      }
    }
    __syncthreads();
  }
}

// ---------------- K6: global bitonic pass for big segments (b128, grid-stride, early-exit)
__global__ __launch_bounds__(256) void k_gpass(
    u32* __restrict__ vbase, const int* __restrict__ pG, const int* __restrict__ pOffG,
    int kk, int j)
{
  u32* base = vbase + (size_t)blockIdx.y * SEG_STRIDE;
  int pb[KCL]; int tot = 0;
#pragma unroll
  for (int c = 0; c < KCL; ++c) {
    pb[c] = tot;
    int pc = pG[c];
    if (pc >= kk) tot += pc >> 1;
  }
  for (int g4 = (blockIdx.x * 256 + threadIdx.x) << 2; g4 < tot; g4 += gridDim.x * 256 * 4) {
    int c = 0;
#pragma unroll
    for (int cc = 1; cc < KCL; ++cc) c += (g4 >= pb[cc]) ? 1 : 0;
    int u = g4 - pb[c];
    int i = ((u & ~(j - 1)) << 1) | (u & (j - 1));
    bool up = ((i & kk) == 0);
    u32* s2 = base + pOffG[c];
    uint4 A = *(const uint4*)(s2 + i);
    uint4 B = *(const uint4*)(s2 + i + j);
    CS(A.x, B.x, up) CS(A.y, B.y, up) CS(A.z, B.z, up) CS(A.w, B.w, up)
    *(uint4*)(s2 + i) = A;
    *(uint4*)(s2 + i + j) = B;
  }
}

// ---------------- K7: finish a big-segment stage (strides <=2048) in LDS (early-exit)
// NOTE: chunks needing finish can be up to sum(p)/CHUNK4 <= 64 -> launch 64 x-blocks.
__global__ __launch_bounds__(256, 8) void k_gfinish(
    u32* __restrict__ vbase, const int* __restrict__ pG, const int* __restrict__ pOffG, int kk)
{
  __shared__ __align__(16) u32 lds[CHUNK4];
  int t = blockIdx.x, c = -1, sub = 0, acc = 0;
  for (int cc = 0; cc < KCL; ++cc) {
    int pc = pG[cc];
    if (pc < kk) continue;
    int nc = pc / CHUNK4;
    if (t < acc + nc) { c = cc; sub = t - acc; break; }
    acc += nc;
  }
  if (c < 0) return;
  u32 gb = (u32)sub * (u32)CHUNK4;
  bool up = ((gb & (u32)kk) == 0);
  u32* seg = vbase + (size_t)blockIdx.y * SEG_STRIDE + pOffG[c] + gb;
  u32 tid = threadIdx.x;
  u32 bas = tid << 4;

  {
    const uint4* sp4 = (const uint4*)(seg + bas);
    uint4 a0 = sp4[0], a1 = sp4[1], a2 = sp4[2], a3 = sp4[3];
    uint4* l4 = (uint4*)&lds[bas];
    l4[0] = a0; l4[1] = a1; l4[2] = a2; l4[3] = a3;
  }
  __syncthreads();
  for (u32 j = CHUNK4 >> 1; j >= 16; j >>= 1) {
    for (u32 p4 = tid << 2; p4 < (CHUNK4 >> 1); p4 += 256 * 4) {
      u32 i = ((p4 & ~(j - 1)) << 1) | (p4 & (j - 1));
      uint4 A = *(const uint4*)&lds[i];
      uint4 B = *(const uint4*)&lds[i + j];
      CS(A.x, B.x, up) CS(A.y, B.y, up) CS(A.z, B.z, up) CS(A.w, B.w, up)
      *(uint4*)&lds[i] = A;
      *(uint4*)&lds[i + j] = B;
    }
    __syncthreads();
  }
  {
    u32 r0,r1,r2,r3,r4,r5,r6,r7,r8,r9,r10,r11,r12,r13,r14,r15;
    const uint4* l4 = (const uint4*)&lds[bas];
    uint4 a0 = l4[0], a1 = l4[1], a2 = l4[2], a3 = l4[3];
    REGS_FROM4(a0, a1, a2, a3);
    MERGE16(up);
    uint4* o4 = (uint4*)(seg + bas);
    o4[0] = make_uint4(r0,r1,r2,r3);   o4[1] = make_uint4(r4,r5,r6,r7);
    o4[2] = make_uint4(r8,r9,r10,r11); o4[3] = make_uint4(r12,r13,r14,r15);
  }
}

// ---------------- K8: pair sorted X/T per (cluster,dim), weighted |diff| reduce
__global__ __launch_bounds__(256) void k_reduce(
    const u32* __restrict__ valX, const u32* __restrict__ valT,
    const int* __restrict__ pOffG, const int* __restrict__ mG,
    const float* __restrict__ wG, float* __restrict__ lossAcc, int Dbc)
{
  __shared__ int spOff[KCL + 1];
  __shared__ int sm[KCL];
  __shared__ float swt[KCL];
  __shared__ float red[256];
  int tid = threadIdx.x;
  if (tid <= KCL) spOff[tid] = pOffG[tid];
  if (tid < KCL) { sm[tid] = mG[tid]; swt[tid] = wG[tid]; }
  __syncthreads();
  int d = blockIdx.y;
  const u32* vx = valX + (size_t)d * SEG_STRIDE;
  const u32* vt = valT + (size_t)d * SEG_STRIDE;
  int P16 = spOff[KCL];
  float s = 0.f;
  for (int pos = blockIdx.x * 256 + tid; pos < P16; pos += gridDim.x * 256) {
    int c = 0;
#pragma unroll
    for (int cc = 1; cc < KCL; ++cc) c += (pos >= spOff[cc]) ? 1 : 0;
    int rel = pos - spOff[c];
    if (rel < sm[c]) {
      float a = dec_f(vx[pos]), b = dec_f(vt[pos]);
      s += fabsf(a - b) * swt[c];
    }
  }
  red[tid] = s;
  __syncthreads();
  for (int st = 128; st > 0; st >>= 1) {
    if (tid < st) red[tid] += red[tid + st];
    __syncthreads();
  }
  if (tid == 0) atomicAdd(lossAcc, red[0]);
}

// ---------------- K9: final scalar
__global__ void k_final(const float* __restrict__ lossAcc, const float* __restrict__ loss_fil,
                        float* __restrict__ out)
{
  out[0] = *lossAcc + *loss_fil;
}

extern "C" void kernel_launch(void* const* d_in, const int* in_sizes, int n_in,
                              void* d_out, int out_size, void* d_ws, size_t ws_size,
                              hipStream_t stream)
{
  const float* x       = (const float*)d_in[0];
  const float* centers = (const float*)d_in[1];
  const float* ftarget = (const float*)d_in[2];
  const float* tgt     = (const float*)d_in[3];
  const int*   predT   = (const int*)d_in[4];
  float* out = (float*)d_out;

  char* ws = (char*)d_ws;
  float* fill_sum = (float*)(ws + 0);       // 16 f (zeroed)
  float* lossAcc  = (float*)(ws + 64);      // zeroed
  float* loss_fil = (float*)(ws + 68);      // zeroed
  int*   m_buf    = (int*)(ws + 128);
  float* w_buf    = (float*)(ws + 192);
  int*   p_buf    = (int*)(ws + 256);
  int*   pOff     = (int*)(ws + 320);       // 17 ints
  int*   padOff   = (int*)(ws + 400);       // 17 ints
  u32* histX = (u32*)(ws + 512);            // 512*16*4 = 32768
  u32* histT = (u32*)(ws + 512 + 32768);
  u32* baseX = (u32*)(ws + 512 + 65536);
  u32* baseT = (u32*)(ws + 512 + 98304);
  int* predX = (int*)(ws + 131584);         // 524288
  int* rankX = (int*)(ws + 655872);
  int* rankT = (int*)(ws + 1180160);
  u32* vbase = (u32*)(ws + VOFF);

  size_t avail_elems = (ws_size > VOFF) ? ((ws_size - VOFF) / 4) : 0;
  int Db = (int)(avail_elems / (2ull * SEG_STRIDE));
  if (Db > DIMS) Db = DIMS;
  if (Db >= 4) Db &= ~3;
  if (Db < 1) Db = 1;

  hipMemsetAsync(ws, 0, 128, stream);
  k_assign<<<NBLK, 256, 0, stream>>>(x, centers, predT, predX, fill_sum, histX, histT);
  k_scan<<<1, 512, 0, stream>>>(histX, histT, baseX, baseT, fill_sum, ftarget,
                                m_buf, w_buf, p_buf, pOff, padOff, loss_fil);
  k_rank<<<NBLK, 256, 0, stream>>>(predX, predT, baseX, baseT, m_buf, rankX, rankT);

  for (int d0 = 0; d0 < DIMS; d0 += Db) {
    int Dbc = (Db < DIMS - d0) ? Db : (DIMS - d0);
    u32* valX = vbase;
    u32* valT = vbase + (size_t)Dbc * SEG_STRIDE;
    k_pad<<<dim3(16, 2 * Dbc), 256, 0, stream>>>(vbase, pOff, padOff, m_buf);
    k_scatter<<<NBLK, 256, 0, stream>>>(x, tgt, predX, predT, rankX, rankT, pOff,
                                        valX, valT, d0, Dbc);
    // chunks worst case: sum max(1, p/4096) <= ~79 -> 96 x-blocks (early-exit extras)
    k_local_sort<<<dim3(96, 2 * Dbc), 256, 0, stream>>>(vbase, p_buf, pOff);
    // fallback merge stages for clusters with p > 4096 (early-exit when none)
    for (int kk = 2 * CHUNK4; kk <= N_ROWS; kk <<= 1) {
      for (int j = kk >> 1; j >= CHUNK4; j >>= 1)
        k_gpass<<<dim3(32, 2 * Dbc), 256, 0, stream>>>(vbase, p_buf, pOff, kk, j);
      // chunks needing finish <= sum(p)/CHUNK4 <= 64
      k_gfinish<<<dim3(64, 2 * Dbc), 256, 0, stream>>>(vbase, p_buf, pOff, kk);
    }
    k_reduce<<<dim3(32, Dbc), 256, 0, stream>>>(valX, valT, pOff, m_buf, w_buf, lossAcc, Dbc);
  }
  k_final<<<1, 1, 0, stream>>>(lossAcc, loss_fil, out);
}

// Round 6
// 867.043 us; speedup vs baseline: 1.8947x; 1.3003x over previous
//
#include <hip/hip_runtime.h>
#include <stdint.h>

#define N_ROWS 131072
#define DIMS 64
#define KCL 16
#define BETA 4.0f
#define NBLK 512            // N_ROWS / 256
#define LCH 8192            // elements per LDS sort chunk (8192 * 4B = 32KB LDS)
#define SEG_STRIDE 263168   // u32 elements per (dim,side): >= worst-case sum of padded cluster sizes
#define VOFF (1u<<21)

typedef unsigned long long u64;
typedef unsigned int u32;

__device__ __forceinline__ u32 enc_f(float f) {
  u32 u = __float_as_uint(f);
  return (u & 0x80000000u) ? ~u : (u | 0x80000000u);
}
__device__ __forceinline__ float dec_f(u32 e) {
  u32 u = (e & 0x80000000u) ? (e & 0x7FFFFFFFu) : ~e;
  return __uint_as_float(u);
}
// unit (uint4) granularity bank swizzle: spreads 8 unit-positions across rows
__device__ __forceinline__ u32 U4(u32 u) { return u ^ ((u >> 3) & 7u); }

// compare-swap: dd=true -> ascending (min at first arg)
#define CS(a,b,dd) { u32 _mn = min(a,b), _mx = max(a,b); a = (dd)?_mn:_mx; b = (dd)?_mx:_mn; }

// bitonic merge of 16 named regs, all comparators direction D (strides 8,4,2,1)
#define M16G(a,b,c,d,e,f,g,h,i2,j2,k2,l,m,n,o,p,D) \
  CS(a,i2,D) CS(b,j2,D) CS(c,k2,D) CS(d,l,D) CS(e,m,D) CS(f,n,D) CS(g,o,D) CS(h,p,D) \
  CS(a,e,D)  CS(b,f,D)  CS(c,g,D)  CS(d,h,D) CS(i2,m,D) CS(j2,n,D) CS(k2,o,D) CS(l,p,D) \
  CS(a,c,D)  CS(b,d,D)  CS(e,g,D)  CS(f,h,D) CS(i2,k2,D) CS(j2,l,D) CS(m,o,D) CS(n,p,D) \
  CS(a,b,D)  CS(c,d,D)  CS(e,f,D)  CS(g,h,D) CS(i2,j2,D) CS(k2,l,D) CS(m,n,D) CS(o,p,D)

// full bitonic sort of 16 named regs with final direction D
#define SORT16G(a,b,c,d,e,f,g,h,i2,j2,k2,l,m,n,o,p,D) \
  CS(a,b,D) CS(c,d,!(D)) CS(e,f,D) CS(g,h,!(D)) CS(i2,j2,D) CS(k2,l,!(D)) CS(m,n,D) CS(o,p,!(D)) \
  CS(a,c,D) CS(b,d,D) CS(e,g,!(D)) CS(f,h,!(D)) CS(i2,k2,D) CS(j2,l,D) CS(m,o,!(D)) CS(n,p,!(D)) \
  CS(a,b,D) CS(c,d,D) CS(e,f,!(D)) CS(g,h,!(D)) CS(i2,j2,D) CS(k2,l,D) CS(m,n,!(D)) CS(o,p,!(D)) \
  CS(a,e,D) CS(b,f,D) CS(c,g,D) CS(d,h,D) CS(i2,m,!(D)) CS(j2,n,!(D)) CS(k2,o,!(D)) CS(l,p,!(D)) \
  CS(a,c,D) CS(b,d,D) CS(e,g,D) CS(f,h,D) CS(i2,k2,!(D)) CS(j2,l,!(D)) CS(m,o,!(D)) CS(n,p,!(D)) \
  CS(a,b,D) CS(c,d,D) CS(e,f,D) CS(g,h,D) CS(i2,j2,!(D)) CS(k2,l,!(D)) CS(m,n,!(D)) CS(o,p,!(D)) \
  M16G(a,b,c,d,e,f,g,h,i2,j2,k2,l,m,n,o,p,D)

// bitonic merge of 32 named regs direction D (strides 16..1)
#define MERGE32(D) \
  CS(r0,r16,D) CS(r1,r17,D) CS(r2,r18,D) CS(r3,r19,D) CS(r4,r20,D) CS(r5,r21,D) CS(r6,r22,D) CS(r7,r23,D) \
  CS(r8,r24,D) CS(r9,r25,D) CS(r10,r26,D) CS(r11,r27,D) CS(r12,r28,D) CS(r13,r29,D) CS(r14,r30,D) CS(r15,r31,D) \
  M16G(r0,r1,r2,r3,r4,r5,r6,r7,r8,r9,r10,r11,r12,r13,r14,r15,D) \
  M16G(r16,r17,r18,r19,r20,r21,r22,r23,r24,r25,r26,r27,r28,r29,r30,r31,D)

// full bitonic sort of 32 named regs, final direction D
#define SORT32(D) \
  SORT16G(r0,r1,r2,r3,r4,r5,r6,r7,r8,r9,r10,r11,r12,r13,r14,r15,D) \
  SORT16G(r16,r17,r18,r19,r20,r21,r22,r23,r24,r25,r26,r27,r28,r29,r30,r31,!(D)) \
  MERGE32(D)

#define LOADTILE(src) \
  { uint4 _a0=src[U4(ub+0)],_a1=src[U4(ub+1)],_a2=src[U4(ub+2)],_a3=src[U4(ub+3)]; \
    uint4 _a4=src[U4(ub+4)],_a5=src[U4(ub+5)],_a6=src[U4(ub+6)],_a7=src[U4(ub+7)]; \
    r0=_a0.x;r1=_a0.y;r2=_a0.z;r3=_a0.w; r4=_a1.x;r5=_a1.y;r6=_a1.z;r7=_a1.w; \
    r8=_a2.x;r9=_a2.y;r10=_a2.z;r11=_a2.w; r12=_a3.x;r13=_a3.y;r14=_a3.z;r15=_a3.w; \
    r16=_a4.x;r17=_a4.y;r18=_a4.z;r19=_a4.w; r20=_a5.x;r21=_a5.y;r22=_a5.z;r23=_a5.w; \
    r24=_a6.x;r25=_a6.y;r26=_a6.z;r27=_a6.w; r28=_a7.x;r29=_a7.y;r30=_a7.z;r31=_a7.w; }

#define STORETILE(dst) \
  { dst[U4(ub+0)]=make_uint4(r0,r1,r2,r3);    dst[U4(ub+1)]=make_uint4(r4,r5,r6,r7); \
    dst[U4(ub+2)]=make_uint4(r8,r9,r10,r11);  dst[U4(ub+3)]=make_uint4(r12,r13,r14,r15); \
    dst[U4(ub+4)]=make_uint4(r16,r17,r18,r19);dst[U4(ub+5)]=make_uint4(r20,r21,r22,r23); \
    dst[U4(ub+6)]=make_uint4(r24,r25,r26,r27);dst[U4(ub+7)]=make_uint4(r28,r29,r30,r31); }

// ---------------- K1: cluster assign + softmax filling + per-block histograms
__global__ __launch_bounds__(256) void k_assign(
    const float* __restrict__ x, const float* __restrict__ centers,
    const int* __restrict__ predT, int* __restrict__ predX,
    float* __restrict__ fill_sum, u32* __restrict__ histX, u32* __restrict__ histT)
{
  __shared__ float c[KCL][DIMS];
  __shared__ float cn[KCL];
  __shared__ float fs[KCL];
  __shared__ u32 hx[KCL], ht[KCL];
  int tid = threadIdx.x;
  for (int t = tid; t < KCL * DIMS; t += 256) c[t / DIMS][t % DIMS] = centers[t];
  if (tid < KCL) { fs[tid] = 0.f; hx[tid] = 0; ht[tid] = 0; }
  __syncthreads();
  if (tid < KCL) {
    float s = 0.f;
    for (int d = 0; d < DIMS; ++d) s += c[tid][d] * c[tid][d];
    cn[tid] = s;
  }
  __syncthreads();
  int i = blockIdx.x * 256 + tid;
  const float4* xr = (const float4*)(x + (size_t)i * DIMS);
  float dot[KCL];
#pragma unroll
  for (int k = 0; k < KCL; ++k) dot[k] = 0.f;
  for (int t = 0; t < DIMS / 4; ++t) {
    float4 v = xr[t];
#pragma unroll
    for (int k = 0; k < KCL; ++k)
      dot[k] += v.x * c[k][4 * t] + v.y * c[k][4 * t + 1] + v.z * c[k][4 * t + 2] + v.w * c[k][4 * t + 3];
  }
  float sc[KCL];
  float smin = 3.0e38f; int kmin = 0;
#pragma unroll
  for (int k = 0; k < KCL; ++k) {
    sc[k] = cn[k] - 2.f * dot[k];
    if (sc[k] < smin) { smin = sc[k]; kmin = k; }
  }
  float e[KCL]; float esum = 0.f;
#pragma unroll
  for (int k = 0; k < KCL; ++k) { e[k] = expf(-BETA * (sc[k] - smin)); esum += e[k]; }
  float inv = 1.f / esum;
#pragma unroll
  for (int k = 0; k < KCL; ++k) atomicAdd(&fs[k], e[k] * inv);
  predX[i] = kmin;
  atomicAdd(&hx[kmin], 1u);
  atomicAdd(&ht[predT[i]], 1u);
  __syncthreads();
  if (tid < KCL) {
    histX[blockIdx.x * KCL + tid] = hx[tid];
    histT[blockIdx.x * KCL + tid] = ht[tid];
    atomicAdd(&fill_sum[tid], fs[tid]);
  }
}

// ---------------- K2: scan hists -> bases, totals, m, w, p (pow2 pad), pOff, padOff, loss_fil
__global__ __launch_bounds__(512) void k_scan(
    const u32* __restrict__ histX, const u32* __restrict__ histT,
    u32* __restrict__ baseX, u32* __restrict__ baseT,
    const float* __restrict__ fill_sum, const float* __restrict__ ftarget,
    int* __restrict__ m_out, float* __restrict__ w_out,
    int* __restrict__ p_out, int* __restrict__ pOff_out, int* __restrict__ padOff_out,
    float* __restrict__ loss_fil)
{
  __shared__ u32 part[2][KCL][17];
  __shared__ u32 tot[2][KCL];
  __shared__ float sq[KCL];
  __shared__ int sp[KCL];
  __shared__ int smv[KCL];
  int tid = threadIdx.x;
  int side = tid >> 8;
  int rem = tid & 255;
  int c = rem >> 4;
  int sub = rem & 15;
  const u32* hist = side ? histT : histX;
  u32* base = side ? baseT : baseX;
  int b0 = sub * 32;
  u32 s = 0;
  for (int b = b0; b < b0 + 32; ++b) s += hist[b * KCL + c];
  part[side][c][sub] = s;
  __syncthreads();
  if (sub == 0) {
    u32 run = 0;
    for (int t = 0; t < 16; ++t) { u32 v = part[side][c][t]; part[side][c][t] = run; run += v; }
    tot[side][c] = run;
  }
  __syncthreads();
  u32 run = part[side][c][sub];
  for (int b = b0; b < b0 + 32; ++b) { base[b * KCL + c] = run; run += hist[b * KCL + c]; }
  if (tid < KCL) {
    int m = min((int)tot[0][tid], (int)tot[1][tid]);
    m_out[tid] = m;
    smv[tid] = m;
    w_out[tid] = (m > 0) ? 1.f / ((float)m * (float)DIMS) : 0.f;
    int pp = 32;
    while (pp < m) pp <<= 1;
    sp[tid] = pp;
    p_out[tid] = pp;
    float d = fill_sum[tid] / (float)N_ROWS - ftarget[tid];
    sq[tid] = d * d;
  }
  __syncthreads();
  if (tid == 0) {
    float s2 = 0.f;
    int acc = 0, pacc = 0;
    for (int k = 0; k < KCL; ++k) {
      s2 += sq[k];
      pOff_out[k] = acc;
      acc += sp[k];
      padOff_out[k] = pacc;
      pacc += sp[k] - smv[k];
    }
    pOff_out[KCL] = acc;
    padOff_out[KCL] = pacc;
    *loss_fil = s2 / (float)KCL;
  }
}

// ---------------- K3: ordered within-cluster rank (-1 if not kept)
__global__ __launch_bounds__(256) void k_rank(
    const int* __restrict__ predX, const int* __restrict__ predT,
    const u32* __restrict__ baseX, const u32* __restrict__ baseT,
    const int* __restrict__ m, int* __restrict__ rankX, int* __restrict__ rankT)
{
  __shared__ int wcX[4][KCL], wcT[4][KCL];
  int tid = threadIdx.x;
  int lane = tid & 63, wave = tid >> 6;
  int i = blockIdx.x * 256 + tid;
  int kx = predX[i], kt = predT[i];
  u64 below = (1ull << lane) - 1ull;
  int lrX = 0, lrT = 0;
  for (int cc = 0; cc < KCL; ++cc) {
    u64 mx = __ballot(kx == cc);
    u64 mt = __ballot(kt == cc);
    if (kx == cc) lrX = __popcll(mx & below);
    if (kt == cc) lrT = __popcll(mt & below);
    if (lane == 0) { wcX[wave][cc] = __popcll(mx); wcT[wave][cc] = __popcll(mt); }
  }
  __syncthreads();
  int wbX = 0, wbT = 0;
  for (int w2 = 0; w2 < wave; ++w2) { wbX += wcX[w2][kx]; wbT += wcT[w2][kt]; }
  int rX = (int)baseX[blockIdx.x * KCL + kx] + wbX + lrX;
  int rT = (int)baseT[blockIdx.x * KCL + kt] + wbT + lrT;
  rankX[i] = (rX < m[kx]) ? rX : -1;
  rankT[i] = (rT < m[kt]) ? rT : -1;
}

// ---------------- K3b: write 0xFF pads only into [pOff+m, pOff+p) per segment
__global__ __launch_bounds__(256) void k_pad(
    u32* __restrict__ vbase, const int* __restrict__ pOffG,
    const int* __restrict__ padOffG, const int* __restrict__ mG)
{
  __shared__ int sOff[KCL];
  __shared__ int sPad[KCL + 1];
  __shared__ int sM[KCL];
  int tid = threadIdx.x;
  if (tid < KCL) { sOff[tid] = pOffG[tid]; sM[tid] = mG[tid]; }
  if (tid <= KCL) sPad[tid] = padOffG[tid];
  __syncthreads();
  int tot = sPad[KCL];
  u32* seg = vbase + (size_t)blockIdx.y * SEG_STRIDE;
  for (int tt = blockIdx.x * 256 + tid; tt < tot; tt += gridDim.x * 256) {
    int c = 0;
#pragma unroll
    for (int cc = 1; cc < KCL; ++cc) c += (tt >= sPad[cc]) ? 1 : 0;
    seg[sOff[c] + sM[c] + (tt - sPad[c])] = 0xFFFFFFFFu;
  }
}

// ---------------- K4: scatter kept encoded values into cluster-partitioned dim arrays
__global__ __launch_bounds__(256) void k_scatter(
    const float* __restrict__ x, const float* __restrict__ tgt,
    const int* __restrict__ predX, const int* __restrict__ predT,
    const int* __restrict__ rankX, const int* __restrict__ rankT,
    const int* __restrict__ pOffG,
    u32* __restrict__ valX, u32* __restrict__ valT, int d0, int Dbc)
{
  __shared__ int spOff[KCL + 1];
  int tid = threadIdx.x;
  if (tid <= KCL) spOff[tid] = pOffG[tid];
  __syncthreads();
  int i = blockIdx.x * 256 + tid;
  int cx = predX[i], rx = rankX[i];
  int ct = predT[i], rt = rankT[i];
  bool vec = ((Dbc & 3) == 0);
  if (rx >= 0) {
    size_t pos = (size_t)spOff[cx] + rx;
    const float* xr = x + (size_t)i * DIMS + d0;
    if (vec) {
      const float4* x4 = (const float4*)xr;
      for (int d = 0; d < Dbc; d += 4) {
        float4 v = x4[d >> 2];
        valX[(size_t)(d + 0) * SEG_STRIDE + pos] = enc_f(v.x);
        valX[(size_t)(d + 1) * SEG_STRIDE + pos] = enc_f(v.y);
        valX[(size_t)(d + 2) * SEG_STRIDE + pos] = enc_f(v.z);
        valX[(size_t)(d + 3) * SEG_STRIDE + pos] = enc_f(v.w);
      }
    } else {
      for (int d = 0; d < Dbc; ++d) valX[(size_t)d * SEG_STRIDE + pos] = enc_f(xr[d]);
    }
  }
  if (rt >= 0) {
    size_t pos = (size_t)spOff[ct] + rt;
    const float* tr = tgt + (size_t)i * DIMS + d0;
    if (vec) {
      const float4* t4 = (const float4*)tr;
      for (int d = 0; d < Dbc; d += 4) {
        float4 v = t4[d >> 2];
        valT[(size_t)(d + 0) * SEG_STRIDE + pos] = enc_f(v.x);
        valT[(size_t)(d + 1) * SEG_STRIDE + pos] = enc_f(v.y);
        valT[(size_t)(d + 2) * SEG_STRIDE + pos] = enc_f(v.z);
        valT[(size_t)(d + 3) * SEG_STRIDE + pos] = enc_f(v.w);
      }
    } else {
      for (int d = 0; d < Dbc; ++d) valT[(size_t)d * SEG_STRIDE + pos] = enc_f(tr[d]);
    }
  }
}

// ---------------- K5: per-chunk LDS bitonic sort; 256 thr, 32 regs/thread, swizzled b128
__global__ __launch_bounds__(256, 4) void k_local_sort(
    u32* __restrict__ vbase, const int* __restrict__ pG, const int* __restrict__ pOffG)
{
  __shared__ __align__(16) u32 lds[LCH];
  uint4* lds4 = (uint4*)lds;
  int t = blockIdx.x, c = -1, sub = 0, acc = 0;
  for (int cc = 0; cc < KCL; ++cc) {
    int pc0 = pG[cc];
    int nc = (pc0 > LCH) ? (pc0 / LCH) : 1;
    if (t < acc + nc) { c = cc; sub = t - acc; break; }
    acc += nc;
  }
  if (c < 0) return;
  int pc = pG[c];
  u32 CH = (u32)min(pc, LCH);
  u32 gb = (u32)sub * (u32)LCH;
  u32* seg = vbase + (size_t)blockIdx.y * SEG_STRIDE + pOffG[c] + gb;
  uint4* gp4 = (uint4*)seg;
  u32 tid = threadIdx.x;
  u32 ub = tid << 3;           // first unit of this thread's 32-elem tile
  u32 bas = tid << 5;          // first element index
  bool act = (bas < CH);
  u32 r0,r1,r2,r3,r4,r5,r6,r7,r8,r9,r10,r11,r12,r13,r14,r15;
  u32 r16,r17,r18,r19,r20,r21,r22,r23,r24,r25,r26,r27,r28,r29,r30,r31;

  // coalesced global -> LDS (swizzled)
  for (u32 uu = tid; (uu << 2) < CH; uu += 256) lds4[U4(uu)] = gp4[uu];
  __syncthreads();

  if (act) {
    LOADTILE(lds4);
    bool D = (((gb + bas) & 32u) == 0u);
    SORT32(D);
    STORETILE(lds4);
  }
  __syncthreads();

  for (u32 k = 64; k <= CH; k <<= 1) {
    for (u32 j = k >> 1; j >= 32; j >>= 1) {
      for (u32 p4 = tid << 2; p4 < (CH >> 1); p4 += 1024) {
        u32 i = ((p4 & ~(j - 1)) << 1) | (p4 & (j - 1));
        bool up = (((gb + i) & k) == 0);
        u32 ua = U4(i >> 2), ubx = U4((i + j) >> 2);
        uint4 A = lds4[ua];
        uint4 B = lds4[ubx];
        CS(A.x, B.x, up) CS(A.y, B.y, up) CS(A.z, B.z, up) CS(A.w, B.w, up)
        lds4[ua] = A;
        lds4[ubx] = B;
      }
      __syncthreads();
    }
    if (act) {
      LOADTILE(lds4);
      bool D = (((gb + bas) & k) == 0);
      MERGE32(D);
      STORETILE(lds4);
    }
    __syncthreads();
  }

  // coalesced LDS -> global
  for (u32 uu = tid; (uu << 2) < CH; uu += 256) gp4[uu] = lds4[U4(uu)];
}

// ---------------- K6: global bitonic pass for big segments (b128, grid-stride, early-exit)
__global__ __launch_bounds__(256) void k_gpass(
    u32* __restrict__ vbase, const int* __restrict__ pG, const int* __restrict__ pOffG,
    int kk, int j)
{
  u32* base = vbase + (size_t)blockIdx.y * SEG_STRIDE;
  int pb[KCL]; int tot = 0;
#pragma unroll
  for (int c = 0; c < KCL; ++c) {
    pb[c] = tot;
    int pc = pG[c];
    if (pc >= kk) tot += pc >> 1;
  }
  for (int g4 = (blockIdx.x * 256 + threadIdx.x) << 2; g4 < tot; g4 += gridDim.x * 256 * 4) {
    int c = 0;
#pragma unroll
    for (int cc = 1; cc < KCL; ++cc) c += (g4 >= pb[cc]) ? 1 : 0;
    int u = g4 - pb[c];
    int i = ((u & ~(j - 1)) << 1) | (u & (j - 1));
    bool up = ((i & kk) == 0);
    u32* s2 = base + pOffG[c];
    uint4 A = *(const uint4*)(s2 + i);
    uint4 B = *(const uint4*)(s2 + i + j);
    CS(A.x, B.x, up) CS(A.y, B.y, up) CS(A.z, B.z, up) CS(A.w, B.w, up)
    *(uint4*)(s2 + i) = A;
    *(uint4*)(s2 + i + j) = B;
  }
}

// ---------------- K7: finish big-segment stage (strides <=4096) in LDS (early-exit)
__global__ __launch_bounds__(256, 4) void k_gfinish(
    u32* __restrict__ vbase, const int* __restrict__ pG, const int* __restrict__ pOffG, int kk)
{
  __shared__ __align__(16) u32 lds[LCH];
  uint4* lds4 = (uint4*)lds;
  int t = blockIdx.x, c = -1, sub = 0, acc = 0;
  for (int cc = 0; cc < KCL; ++cc) {
    int pc = pG[cc];
    if (pc < kk) continue;
    int nc = pc / LCH;
    if (t < acc + nc) { c = cc; sub = t - acc; break; }
    acc += nc;
  }
  if (c < 0) return;
  u32 gb = (u32)sub * (u32)LCH;
  bool up = ((gb & (u32)kk) == 0);
  u32* seg = vbase + (size_t)blockIdx.y * SEG_STRIDE + pOffG[c] + gb;
  uint4* gp4 = (uint4*)seg;
  u32 tid = threadIdx.x;
  u32 ub = tid << 3;
  u32 r0,r1,r2,r3,r4,r5,r6,r7,r8,r9,r10,r11,r12,r13,r14,r15;
  u32 r16,r17,r18,r19,r20,r21,r22,r23,r24,r25,r26,r27,r28,r29,r30,r31;

  for (u32 uu = tid; uu < LCH / 4; uu += 256) lds4[U4(uu)] = gp4[uu];
  __syncthreads();
  for (u32 j = LCH >> 1; j >= 32; j >>= 1) {
    for (u32 p4 = tid << 2; p4 < (LCH >> 1); p4 += 1024) {
      u32 i = ((p4 & ~(j - 1)) << 1) | (p4 & (j - 1));
      u32 ua = U4(i >> 2), ubx = U4((i + j) >> 2);
      uint4 A = lds4[ua];
      uint4 B = lds4[ubx];
      CS(A.x, B.x, up) CS(A.y, B.y, up) CS(A.z, B.z, up) CS(A.w, B.w, up)
      lds4[ua] = A;
      lds4[ubx] = B;
    }
    __syncthreads();
  }
  {
    LOADTILE(lds4);
    MERGE32(up);
    STORETILE(lds4);
  }
  __syncthreads();
  for (u32 uu = tid; uu < LCH / 4; uu += 256) gp4[uu] = lds4[U4(uu)];
}

// ---------------- K8: pair sorted X/T per (cluster,dim), weighted |diff| reduce
__global__ __launch_bounds__(256) void k_reduce(
    const u32* __restrict__ valX, const u32* __restrict__ valT,
    const int* __restrict__ pOffG, const int* __restrict__ mG,
    const float* __restrict__ wG, float* __restrict__ lossAcc, int Dbc)
{
  __shared__ int spOff[KCL + 1];
  __shared__ int sm[KCL];
  __shared__ float swt[KCL];
  __shared__ float red[256];
  int tid = threadIdx.x;
  if (tid <= KCL) spOff[tid] = pOffG[tid];
  if (tid < KCL) { sm[tid] = mG[tid]; swt[tid] = wG[tid]; }
  __syncthreads();
  int d = blockIdx.y;
  const u32* vx = valX + (size_t)d * SEG_STRIDE;
  const u32* vt = valT + (size_t)d * SEG_STRIDE;
  int P16 = spOff[KCL];
  float s = 0.f;
  for (int pos = blockIdx.x * 256 + tid; pos < P16; pos += gridDim.x * 256) {
    int c = 0;
#pragma unroll
    for (int cc = 1; cc < KCL; ++cc) c += (pos >= spOff[cc]) ? 1 : 0;
    int rel = pos - spOff[c];
    if (rel < sm[c]) {
      float a = dec_f(vx[pos]), b = dec_f(vt[pos]);
      s += fabsf(a - b) * swt[c];
    }
  }
  red[tid] = s;
  __syncthreads();
  for (int st = 128; st > 0; st >>= 1) {
    if (tid < st) red[tid] += red[tid + st];
    __syncthreads();
  }
  if (tid == 0) atomicAdd(lossAcc, red[0]);
}

// ---------------- K9: final scalar
__global__ void k_final(const float* __restrict__ lossAcc, const float* __restrict__ loss_fil,
                        float* __restrict__ out)
{
  out[0] = *lossAcc + *loss_fil;
}

extern "C" void kernel_launch(void* const* d_in, const int* in_sizes, int n_in,
                              void* d_out, int out_size, void* d_ws, size_t ws_size,
                              hipStream_t stream)
{
  const float* x       = (const float*)d_in[0];
  const float* centers = (const float*)d_in[1];
  const float* ftarget = (const float*)d_in[2];
  const float* tgt     = (const float*)d_in[3];
  const int*   predT   = (const int*)d_in[4];
  float* out = (float*)d_out;

  char* ws = (char*)d_ws;
  float* fill_sum = (float*)(ws + 0);       // 16 f (zeroed)
  float* lossAcc  = (float*)(ws + 64);      // zeroed
  float* loss_fil = (float*)(ws + 68);      // zeroed
  int*   m_buf    = (int*)(ws + 128);
  float* w_buf    = (float*)(ws + 192);
  int*   p_buf    = (int*)(ws + 256);
  int*   pOff     = (int*)(ws + 320);       // 17 ints
  int*   padOff   = (int*)(ws + 400);       // 17 ints
  u32* histX = (u32*)(ws + 512);            // 512*16*4 = 32768
  u32* histT = (u32*)(ws + 512 + 32768);
  u32* baseX = (u32*)(ws + 512 + 65536);
  u32* baseT = (u32*)(ws + 512 + 98304);
  int* predX = (int*)(ws + 131584);         // 524288
  int* rankX = (int*)(ws + 655872);
  int* rankT = (int*)(ws + 1180160);
  u32* vbase = (u32*)(ws + VOFF);

  size_t avail_elems = (ws_size > VOFF) ? ((ws_size - VOFF) / 4) : 0;
  int Db = (int)(avail_elems / (2ull * SEG_STRIDE));
  if (Db > DIMS) Db = DIMS;
  if (Db >= 4) Db &= ~3;
  if (Db < 1) Db = 1;

  hipMemsetAsync(ws, 0, 128, stream);
  k_assign<<<NBLK, 256, 0, stream>>>(x, centers, predT, predX, fill_sum, histX, histT);
  k_scan<<<1, 512, 0, stream>>>(histX, histT, baseX, baseT, fill_sum, ftarget,
                                m_buf, w_buf, p_buf, pOff, padOff, loss_fil);
  k_rank<<<NBLK, 256, 0, stream>>>(predX, predT, baseX, baseT, m_buf, rankX, rankT);

  for (int d0 = 0; d0 < DIMS; d0 += Db) {
    int Dbc = (Db < DIMS - d0) ? Db : (DIMS - d0);
    u32* valX = vbase;
    u32* valT = vbase + (size_t)Dbc * SEG_STRIDE;
    k_pad<<<dim3(16, 2 * Dbc), 256, 0, stream>>>(vbase, pOff, padOff, m_buf);
    k_scatter<<<NBLK, 256, 0, stream>>>(x, tgt, predX, predT, rankX, rankT, pOff,
                                        valX, valT, d0, Dbc);
    // chunks worst case: sum max(1, p/8192) <= 31 -> 40 x-blocks (extras early-exit)
    k_local_sort<<<dim3(40, 2 * Dbc), 256, 0, stream>>>(vbase, p_buf, pOff);
    // fallback merge stages for clusters with p > 8192 (early-exit when none)
    for (int kk = 2 * LCH; kk <= N_ROWS; kk <<= 1) {
      for (int j = kk >> 1; j >= LCH; j >>= 1)
        k_gpass<<<dim3(32, 2 * Dbc), 256, 0, stream>>>(vbase, p_buf, pOff, kk, j);
      // chunks needing finish <= sum(p)/LCH <= 32
      k_gfinish<<<dim3(32, 2 * Dbc), 256, 0, stream>>>(vbase, p_buf, pOff, kk);
    }
    k_reduce<<<dim3(32, Dbc), 256, 0, stream>>>(valX, valT, pOff, m_buf, w_buf, lossAcc, Dbc);
  }
  k_final<<<1, 1, 0, stream>>>(lossAcc, loss_fil, out);
}

// Round 8
// 844.870 us; speedup vs baseline: 1.9444x; 1.0262x over previous
//
#include <hip/hip_runtime.h>
#include <stdint.h>

#define N_ROWS 131072
#define DIMS 64
#define KCL 16
#define BETA 4.0f
#define NBLK 512            // N_ROWS / 256
#define LCH 8192            // elements per LDS sort chunk (8192 * 4B = 32KB LDS)
#define SEG_STRIDE 263168   // u32 elements per (dim,side): >= worst-case sum of padded cluster sizes
#define VOFF (1u<<21)

typedef unsigned long long u64;
typedef unsigned int u32;

__device__ __forceinline__ u32 enc_f(float f) {
  u32 u = __float_as_uint(f);
  return (u & 0x80000000u) ? ~u : (u | 0x80000000u);
}
__device__ __forceinline__ float dec_f(u32 e) {
  u32 u = (e & 0x80000000u) ? (e & 0x7FFFFFFFu) : ~e;
  return __uint_as_float(u);
}
// unit (uint4) granularity bank swizzle: spreads 8 unit-positions across rows
__device__ __forceinline__ u32 U4(u32 u) { return u ^ ((u >> 3) & 7u); }

// compare-swap: dd=true -> ascending (min at first arg)
#define CS(a,b,dd) { u32 _mn = min(a,b), _mx = max(a,b); a = (dd)?_mn:_mx; b = (dd)?_mx:_mn; }
// component-wise CS on uint4 (valid when stride >= 4 elements)
#define CSV(A,B,D) { CS(A.x,B.x,D) CS(A.y,B.y,D) CS(A.z,B.z,D) CS(A.w,B.w,D) }

// bitonic merge of 16 named regs, all comparators direction D (strides 8,4,2,1)
#define M16G(a,b,c,d,e,f,g,h,i2,j2,k2,l,m,n,o,p,D) \
  CS(a,i2,D) CS(b,j2,D) CS(c,k2,D) CS(d,l,D) CS(e,m,D) CS(f,n,D) CS(g,o,D) CS(h,p,D) \
  CS(a,e,D)  CS(b,f,D)  CS(c,g,D)  CS(d,h,D) CS(i2,m,D) CS(j2,n,D) CS(k2,o,D) CS(l,p,D) \
  CS(a,c,D)  CS(b,d,D)  CS(e,g,D)  CS(f,h,D) CS(i2,k2,D) CS(j2,l,D) CS(m,o,D) CS(n,p,D) \
  CS(a,b,D)  CS(c,d,D)  CS(e,f,D)  CS(g,h,D) CS(i2,j2,D) CS(k2,l,D) CS(m,n,D) CS(o,p,D)

// full bitonic sort of 16 named regs with final direction D
#define SORT16G(a,b,c,d,e,f,g,h,i2,j2,k2,l,m,n,o,p,D) \
  CS(a,b,D) CS(c,d,!(D)) CS(e,f,D) CS(g,h,!(D)) CS(i2,j2,D) CS(k2,l,!(D)) CS(m,n,D) CS(o,p,!(D)) \
  CS(a,c,D) CS(b,d,D) CS(e,g,!(D)) CS(f,h,!(D)) CS(i2,k2,D) CS(j2,l,D) CS(m,o,!(D)) CS(n,p,!(D)) \
  CS(a,b,D) CS(c,d,D) CS(e,f,!(D)) CS(g,h,!(D)) CS(i2,j2,D) CS(k2,l,D) CS(m,n,!(D)) CS(o,p,!(D)) \
  CS(a,e,D) CS(b,f,D) CS(c,g,D) CS(d,h,D) CS(i2,m,!(D)) CS(j2,n,!(D)) CS(k2,o,!(D)) CS(l,p,!(D)) \
  CS(a,c,D) CS(b,d,D) CS(e,g,D) CS(f,h,D) CS(i2,k2,!(D)) CS(j2,l,!(D)) CS(m,o,!(D)) CS(n,p,!(D)) \
  CS(a,b,D) CS(c,d,D) CS(e,f,D) CS(g,h,D) CS(i2,j2,!(D)) CS(k2,l,!(D)) CS(m,n,!(D)) CS(o,p,!(D)) \
  M16G(a,b,c,d,e,f,g,h,i2,j2,k2,l,m,n,o,p,D)

// bitonic merge of 32 named regs direction D (strides 16..1)
#define MERGE32(D) \
  CS(r0,r16,D) CS(r1,r17,D) CS(r2,r18,D) CS(r3,r19,D) CS(r4,r20,D) CS(r5,r21,D) CS(r6,r22,D) CS(r7,r23,D) \
  CS(r8,r24,D) CS(r9,r25,D) CS(r10,r26,D) CS(r11,r27,D) CS(r12,r28,D) CS(r13,r29,D) CS(r14,r30,D) CS(r15,r31,D) \
  M16G(r0,r1,r2,r3,r4,r5,r6,r7,r8,r9,r10,r11,r12,r13,r14,r15,D) \
  M16G(r16,r17,r18,r19,r20,r21,r22,r23,r24,r25,r26,r27,r28,r29,r30,r31,D)

// full bitonic sort of 32 named regs, final direction D
#define SORT32(D) \
  SORT16G(r0,r1,r2,r3,r4,r5,r6,r7,r8,r9,r10,r11,r12,r13,r14,r15,D) \
  SORT16G(r16,r17,r18,r19,r20,r21,r22,r23,r24,r25,r26,r27,r28,r29,r30,r31,!(D)) \
  MERGE32(D)

#define LOADTILE(src) \
  { uint4 _a0=src[U4(ub+0)],_a1=src[U4(ub+1)],_a2=src[U4(ub+2)],_a3=src[U4(ub+3)]; \
    uint4 _a4=src[U4(ub+4)],_a5=src[U4(ub+5)],_a6=src[U4(ub+6)],_a7=src[U4(ub+7)]; \
    r0=_a0.x;r1=_a0.y;r2=_a0.z;r3=_a0.w; r4=_a1.x;r5=_a1.y;r6=_a1.z;r7=_a1.w; \
    r8=_a2.x;r9=_a2.y;r10=_a2.z;r11=_a2.w; r12=_a3.x;r13=_a3.y;r14=_a3.z;r15=_a3.w; \
    r16=_a4.x;r17=_a4.y;r18=_a4.z;r19=_a4.w; r20=_a5.x;r21=_a5.y;r22=_a5.z;r23=_a5.w; \
    r24=_a6.x;r25=_a6.y;r26=_a6.z;r27=_a6.w; r28=_a7.x;r29=_a7.y;r30=_a7.z;r31=_a7.w; }

#define STORETILE(dst) \
  { dst[U4(ub+0)]=make_uint4(r0,r1,r2,r3);    dst[U4(ub+1)]=make_uint4(r4,r5,r6,r7); \
    dst[U4(ub+2)]=make_uint4(r8,r9,r10,r11);  dst[U4(ub+3)]=make_uint4(r12,r13,r14,r15); \
    dst[U4(ub+4)]=make_uint4(r16,r17,r18,r19);dst[U4(ub+5)]=make_uint4(r20,r21,r22,r23); \
    dst[U4(ub+6)]=make_uint4(r24,r25,r26,r27);dst[U4(ub+7)]=make_uint4(r28,r29,r30,r31); }

// ---- fused LDS merge rounds for one bitonic stage k: strides k/2..32 (3-fused),
// then reg-tile strides 16..1 are handled by caller. Direction = ((gb+i)&k)==0
// (also correct for k > CH: constant over the chunk). Ends with __syncthreads().
__device__ __forceinline__ void merge_stage_lds(uint4* lds4, u32 CH, u32 gb, u32 k, u32 tid)
{
  u32 j = k >> 1;
  if (j > (CH >> 1)) j = CH >> 1;
  while (j >= 32) {
    if (j >= 128) {                 // fused strides j, j/2, j/4
      u32 jq = j >> 2, ju = j >> 4;
      for (u32 p = tid << 2; p < (CH >> 3); p += 1024) {
        u32 col = p & (jq - 1);
        u32 i = ((p & ~(jq - 1)) << 3) | col;
        bool up = (((gb + i) & k) == 0);
        u32 bu = i >> 2;
        uint4 A0 = lds4[U4(bu)],          A1 = lds4[U4(bu + ju)],
              A2 = lds4[U4(bu + 2 * ju)], A3 = lds4[U4(bu + 3 * ju)],
              A4 = lds4[U4(bu + 4 * ju)], A5 = lds4[U4(bu + 5 * ju)],
              A6 = lds4[U4(bu + 6 * ju)], A7 = lds4[U4(bu + 7 * ju)];
        CSV(A0,A4,up) CSV(A1,A5,up) CSV(A2,A6,up) CSV(A3,A7,up)      // stride j
        CSV(A0,A2,up) CSV(A1,A3,up) CSV(A4,A6,up) CSV(A5,A7,up)      // stride j/2
        CSV(A0,A1,up) CSV(A2,A3,up) CSV(A4,A5,up) CSV(A6,A7,up)      // stride j/4
        lds4[U4(bu)] = A0;          lds4[U4(bu + ju)] = A1;
        lds4[U4(bu + 2 * ju)] = A2; lds4[U4(bu + 3 * ju)] = A3;
        lds4[U4(bu + 4 * ju)] = A4; lds4[U4(bu + 5 * ju)] = A5;
        lds4[U4(bu + 6 * ju)] = A6; lds4[U4(bu + 7 * ju)] = A7;
      }
      j >>= 3;
    } else if (j == 64) {           // fused strides 64, 32
      for (u32 p = tid << 2; p < (CH >> 2); p += 1024) {
        u32 col = p & 31u;
        u32 i = ((p & ~31u) << 2) | col;
        bool up = (((gb + i) & k) == 0);
        u32 bu = i >> 2;
        uint4 A0 = lds4[U4(bu)],      A1 = lds4[U4(bu + 8)],
              A2 = lds4[U4(bu + 16)], A3 = lds4[U4(bu + 24)];
        CSV(A0,A2,up) CSV(A1,A3,up)                                   // stride 64
        CSV(A0,A1,up) CSV(A2,A3,up)                                   // stride 32
        lds4[U4(bu)] = A0;      lds4[U4(bu + 8)] = A1;
        lds4[U4(bu + 16)] = A2; lds4[U4(bu + 24)] = A3;
      }
      j = 0;
    } else {                        // single stride 32
      for (u32 p = tid << 2; p < (CH >> 1); p += 1024) {
        u32 i = ((p & ~31u) << 1) | (p & 31u);
        bool up = (((gb + i) & k) == 0);
        u32 ua = U4(i >> 2), ub2 = U4((i + 32) >> 2);
        uint4 A = lds4[ua], B = lds4[ub2];
        CSV(A,B,up)
        lds4[ua] = A; lds4[ub2] = B;
      }
      j = 0;
    }
    __syncthreads();
  }
}

// ---------------- K1: cluster assign + softmax filling + per-block histograms
__global__ __launch_bounds__(256) void k_assign(
    const float* __restrict__ x, const float* __restrict__ centers,
    const int* __restrict__ predT, int* __restrict__ predX,
    float* __restrict__ fill_sum, u32* __restrict__ histX, u32* __restrict__ histT)
{
  __shared__ float c[KCL][DIMS];
  __shared__ float cn[KCL];
  __shared__ float fs[KCL];
  __shared__ u32 hx[KCL], ht[KCL];
  int tid = threadIdx.x;
  for (int t = tid; t < KCL * DIMS; t += 256) c[t / DIMS][t % DIMS] = centers[t];
  if (tid < KCL) { fs[tid] = 0.f; hx[tid] = 0; ht[tid] = 0; }
  __syncthreads();
  if (tid < KCL) {
    float s = 0.f;
    for (int d = 0; d < DIMS; ++d) s += c[tid][d] * c[tid][d];
    cn[tid] = s;
  }
  __syncthreads();
  int i = blockIdx.x * 256 + tid;
  const float4* xr = (const float4*)(x + (size_t)i * DIMS);
  float dot[KCL];
#pragma unroll
  for (int k = 0; k < KCL; ++k) dot[k] = 0.f;
  for (int t = 0; t < DIMS / 4; ++t) {
    float4 v = xr[t];
#pragma unroll
    for (int k = 0; k < KCL; ++k)
      dot[k] += v.x * c[k][4 * t] + v.y * c[k][4 * t + 1] + v.z * c[k][4 * t + 2] + v.w * c[k][4 * t + 3];
  }
  float sc[KCL];
  float smin = 3.0e38f; int kmin = 0;
#pragma unroll
  for (int k = 0; k < KCL; ++k) {
    sc[k] = cn[k] - 2.f * dot[k];
    if (sc[k] < smin) { smin = sc[k]; kmin = k; }
  }
  float e[KCL]; float esum = 0.f;
#pragma unroll
  for (int k = 0; k < KCL; ++k) { e[k] = expf(-BETA * (sc[k] - smin)); esum += e[k]; }
  float inv = 1.f / esum;
#pragma unroll
  for (int k = 0; k < KCL; ++k) atomicAdd(&fs[k], e[k] * inv);
  predX[i] = kmin;
  atomicAdd(&hx[kmin], 1u);
  atomicAdd(&ht[predT[i]], 1u);
  __syncthreads();
  if (tid < KCL) {
    histX[blockIdx.x * KCL + tid] = hx[tid];
    histT[blockIdx.x * KCL + tid] = ht[tid];
    atomicAdd(&fill_sum[tid], fs[tid]);
  }
}

// ---------------- K2: scan hists -> bases, totals, m, w, p (pow2 pad), pOff, padOff, loss_fil
__global__ __launch_bounds__(512) void k_scan(
    const u32* __restrict__ histX, const u32* __restrict__ histT,
    u32* __restrict__ baseX, u32* __restrict__ baseT,
    const float* __restrict__ fill_sum, const float* __restrict__ ftarget,
    int* __restrict__ m_out, float* __restrict__ w_out,
    int* __restrict__ p_out, int* __restrict__ pOff_out, int* __restrict__ padOff_out,
    float* __restrict__ loss_fil)
{
  __shared__ u32 part[2][KCL][17];
  __shared__ u32 tot[2][KCL];
  __shared__ float sq[KCL];
  __shared__ int sp[KCL];
  __shared__ int smv[KCL];
  int tid = threadIdx.x;
  int side = tid >> 8;
  int rem = tid & 255;
  int c = rem >> 4;
  int sub = rem & 15;
  const u32* hist = side ? histT : histX;
  u32* base = side ? baseT : baseX;
  int b0 = sub * 32;
  u32 s = 0;
  for (int b = b0; b < b0 + 32; ++b) s += hist[b * KCL + c];
  part[side][c][sub] = s;
  __syncthreads();
  if (sub == 0) {
    u32 run = 0;
    for (int t = 0; t < 16; ++t) { u32 v = part[side][c][t]; part[side][c][t] = run; run += v; }
    tot[side][c] = run;
  }
  __syncthreads();
  u32 run = part[side][c][sub];
  for (int b = b0; b < b0 + 32; ++b) { base[b * KCL + c] = run; run += hist[b * KCL + c]; }
  if (tid < KCL) {
    int m = min((int)tot[0][tid], (int)tot[1][tid]);
    m_out[tid] = m;
    smv[tid] = m;
    w_out[tid] = (m > 0) ? 1.f / ((float)m * (float)DIMS) : 0.f;
    int pp = 32;
    while (pp < m) pp <<= 1;
    sp[tid] = pp;
    p_out[tid] = pp;
    float d = fill_sum[tid] / (float)N_ROWS - ftarget[tid];
    sq[tid] = d * d;
  }
  __syncthreads();
  if (tid == 0) {
    float s2 = 0.f;
    int acc = 0, pacc = 0;
    for (int k = 0; k < KCL; ++k) {
      s2 += sq[k];
      pOff_out[k] = acc;
      acc += sp[k];
      padOff_out[k] = pacc;
      pacc += sp[k] - smv[k];
    }
    pOff_out[KCL] = acc;
    padOff_out[KCL] = pacc;
    *loss_fil = s2 / (float)KCL;
  }
}

// ---------------- K3: ordered within-cluster rank (-1 if not kept)
__global__ __launch_bounds__(256) void k_rank(
    const int* __restrict__ predX, const int* __restrict__ predT,
    const u32* __restrict__ baseX, const u32* __restrict__ baseT,
    const int* __restrict__ m, int* __restrict__ rankX, int* __restrict__ rankT)
{
  __shared__ int wcX[4][KCL], wcT[4][KCL];
  int tid = threadIdx.x;
  int lane = tid & 63, wave = tid >> 6;
  int i = blockIdx.x * 256 + tid;
  int kx = predX[i], kt = predT[i];
  u64 below = (1ull << lane) - 1ull;
  int lrX = 0, lrT = 0;
  for (int cc = 0; cc < KCL; ++cc) {
    u64 mx = __ballot(kx == cc);
    u64 mt = __ballot(kt == cc);
    if (kx == cc) lrX = __popcll(mx & below);
    if (kt == cc) lrT = __popcll(mt & below);
    if (lane == 0) { wcX[wave][cc] = __popcll(mx); wcT[wave][cc] = __popcll(mt); }
  }
  __syncthreads();
  int wbX = 0, wbT = 0;
  for (int w2 = 0; w2 < wave; ++w2) { wbX += wcX[w2][kx]; wbT += wcT[w2][kt]; }
  int rX = (int)baseX[blockIdx.x * KCL + kx] + wbX + lrX;
  int rT = (int)baseT[blockIdx.x * KCL + kt] + wbT + lrT;
  rankX[i] = (rX < m[kx]) ? rX : -1;
  rankT[i] = (rT < m[kt]) ? rT : -1;
}

// ---------------- K3b: write 0xFF pads only into [pOff+m, pOff+p) per segment
__global__ __launch_bounds__(256) void k_pad(
    u32* __restrict__ vbase, const int* __restrict__ pOffG,
    const int* __restrict__ padOffG, const int* __restrict__ mG)
{
  __shared__ int sOff[KCL];
  __shared__ int sPad[KCL + 1];
  __shared__ int sM[KCL];
  int tid = threadIdx.x;
  if (tid < KCL) { sOff[tid] = pOffG[tid]; sM[tid] = mG[tid]; }
  if (tid <= KCL) sPad[tid] = padOffG[tid];
  __syncthreads();
  int tot = sPad[KCL];
  u32* seg = vbase + (size_t)blockIdx.y * SEG_STRIDE;
  for (int tt = blockIdx.x * 256 + tid; tt < tot; tt += gridDim.x * 256) {
    int c = 0;
#pragma unroll
    for (int cc = 1; cc < KCL; ++cc) c += (tt >= sPad[cc]) ? 1 : 0;
    seg[sOff[c] + sM[c] + (tt - sPad[c])] = 0xFFFFFFFFu;
  }
}

// ---------------- K4: scatter kept encoded values into cluster-partitioned dim arrays
__global__ __launch_bounds__(256) void k_scatter(
    const float* __restrict__ x, const float* __restrict__ tgt,
    const int* __restrict__ predX, const int* __restrict__ predT,
    const int* __restrict__ rankX, const int* __restrict__ rankT,
    const int* __restrict__ pOffG,
    u32* __restrict__ valX, u32* __restrict__ valT, int d0, int Dbc)
{
  __shared__ int spOff[KCL + 1];
  int tid = threadIdx.x;
  if (tid <= KCL) spOff[tid] = pOffG[tid];
  __syncthreads();
  int i = blockIdx.x * 256 + tid;
  int cx = predX[i], rx = rankX[i];
  int ct = predT[i], rt = rankT[i];
  bool vec = ((Dbc & 3) == 0);
  if (rx >= 0) {
    size_t pos = (size_t)spOff[cx] + rx;
    const float* xr = x + (size_t)i * DIMS + d0;
    if (vec) {
      const float4* x4 = (const float4*)xr;
      for (int d = 0; d < Dbc; d += 4) {
        float4 v = x4[d >> 2];
        valX[(size_t)(d + 0) * SEG_STRIDE + pos] = enc_f(v.x);
        valX[(size_t)(d + 1) * SEG_STRIDE + pos] = enc_f(v.y);
        valX[(size_t)(d + 2) * SEG_STRIDE + pos] = enc_f(v.z);
        valX[(size_t)(d + 3) * SEG_STRIDE + pos] = enc_f(v.w);
      }
    } else {
      for (int d = 0; d < Dbc; ++d) valX[(size_t)d * SEG_STRIDE + pos] = enc_f(xr[d]);
    }
  }
  if (rt >= 0) {
    size_t pos = (size_t)spOff[ct] + rt;
    const float* tr = tgt + (size_t)i * DIMS + d0;
    if (vec) {
      const float4* t4 = (const float4*)tr;
      for (int d = 0; d < Dbc; d += 4) {
        float4 v = t4[d >> 2];
        valT[(size_t)(d + 0) * SEG_STRIDE + pos] = enc_f(v.x);
        valT[(size_t)(d + 1) * SEG_STRIDE + pos] = enc_f(v.y);
        valT[(size_t)(d + 2) * SEG_STRIDE + pos] = enc_f(v.z);
        valT[(size_t)(d + 3) * SEG_STRIDE + pos] = enc_f(v.w);
      }
    } else {
      for (int d = 0; d < Dbc; ++d) valT[(size_t)d * SEG_STRIDE + pos] = enc_f(tr[d]);
    }
  }
}

// ---------------- K5: per-chunk LDS bitonic sort; 256 thr, 32 regs/thread, fused LDS rounds
__global__ __launch_bounds__(256, 4) void k_local_sort(
    u32* __restrict__ vbase, const int* __restrict__ pG, const int* __restrict__ pOffG)
{
  __shared__ __align__(16) u32 lds[LCH];
  uint4* lds4 = (uint4*)lds;
  int t = blockIdx.x, c = -1, sub = 0, acc = 0;
  for (int cc = 0; cc < KCL; ++cc) {
    int pc0 = pG[cc];
    int nc = (pc0 > LCH) ? (pc0 / LCH) : 1;
    if (t < acc + nc) { c = cc; sub = t - acc; break; }
    acc += nc;
  }
  if (c < 0) return;
  int pc = pG[c];
  u32 CH = (u32)min(pc, LCH);
  u32 gb = (u32)sub * (u32)LCH;
  u32* seg = vbase + (size_t)blockIdx.y * SEG_STRIDE + pOffG[c] + gb;
  uint4* gp4 = (uint4*)seg;
  u32 tid = threadIdx.x;
  u32 ub = tid << 3;           // first unit of this thread's 32-elem tile
  u32 bas = tid << 5;          // first element index
  bool act = (bas < CH);
  u32 r0,r1,r2,r3,r4,r5,r6,r7,r8,r9,r10,r11,r12,r13,r14,r15;
  u32 r16,r17,r18,r19,r20,r21,r22,r23,r24,r25,r26,r27,r28,r29,r30,r31;

  // coalesced global -> LDS (swizzled)
  for (u32 uu = tid; (uu << 2) < CH; uu += 256) lds4[U4(uu)] = gp4[uu];
  __syncthreads();

  if (act) {
    LOADTILE(lds4);
    bool D = (((gb + bas) & 32u) == 0u);
    SORT32(D);
    STORETILE(lds4);
  }
  __syncthreads();

  for (u32 k = 64; k <= CH; k <<= 1) {
    merge_stage_lds(lds4, CH, gb, k, tid);   // strides k/2..32, fused; ends with barrier
    if (act) {
      LOADTILE(lds4);
      bool D = (((gb + bas) & k) == 0);
      MERGE32(D);
      STORETILE(lds4);
    }
    __syncthreads();
  }

  // coalesced LDS -> global
  for (u32 uu = tid; (uu << 2) < CH; uu += 256) gp4[uu] = lds4[U4(uu)];
}

// ---------------- K6: global bitonic pass for big segments (b128, grid-stride, early-exit)
__global__ __launch_bounds__(256) void k_gpass(
    u32* __restrict__ vbase, const int* __restrict__ pG, const int* __restrict__ pOffG,
    int kk, int j)
{
  u32* base = vbase + (size_t)blockIdx.y * SEG_STRIDE;
  int pb[KCL]; int tot = 0;
#pragma unroll
  for (int c = 0; c < KCL; ++c) {
    pb[c] = tot;
    int pc = pG[c];
    if (pc >= kk) tot += pc >> 1;
  }
  for (int g4 = (blockIdx.x * 256 + threadIdx.x) << 2; g4 < tot; g4 += gridDim.x * 256 * 4) {
    int c = 0;
#pragma unroll
    for (int cc = 1; cc < KCL; ++cc) c += (g4 >= pb[cc]) ? 1 : 0;
    int u = g4 - pb[c];
    int i = ((u & ~(j - 1)) << 1) | (u & (j - 1));
    bool up = ((i & kk) == 0);
    u32* s2 = base + pOffG[c];
    uint4 A = *(const uint4*)(s2 + i);
    uint4 B = *(const uint4*)(s2 + i + j);
    CS(A.x, B.x, up) CS(A.y, B.y, up) CS(A.z, B.z, up) CS(A.w, B.w, up)
    *(uint4*)(s2 + i) = A;
    *(uint4*)(s2 + i + j) = B;
  }
}

// ---------------- K7: finish big-segment stage (strides <=4096) in LDS (early-exit)
__global__ __launch_bounds__(256, 4) void k_gfinish(
    u32* __restrict__ vbase, const int* __restrict__ pG, const int* __restrict__ pOffG, int kk)
{
  __shared__ __align__(16) u32 lds[LCH];
  uint4* lds4 = (uint4*)lds;
  int t = blockIdx.x, c = -1, sub = 0, acc = 0;
  for (int cc = 0; cc < KCL; ++cc) {
    int pc = pG[cc];
    if (pc < kk) continue;
    int nc = pc / LCH;
    if (t < acc + nc) { c = cc; sub = t - acc; break; }
    acc += nc;
  }
  if (c < 0) return;
  u32 gb = (u32)sub * (u32)LCH;
  u32* seg = vbase + (size_t)blockIdx.y * SEG_STRIDE + pOffG[c] + gb;
  uint4* gp4 = (uint4*)seg;
  u32 tid = threadIdx.x;
  u32 ub = tid << 3;
  u32 bas = tid << 5;
  u32 r0,r1,r2,r3,r4,r5,r6,r7,r8,r9,r10,r11,r12,r13,r14,r15;
  u32 r16,r17,r18,r19,r20,r21,r22,r23,r24,r25,r26,r27,r28,r29,r30,r31;

  for (u32 uu = tid; uu < LCH / 4; uu += 256) lds4[U4(uu)] = gp4[uu];
  __syncthreads();
  merge_stage_lds(lds4, LCH, gb, (u32)kk, tid);  // direction constant over chunk; fused
  {
    LOADTILE(lds4);
    bool up = (((gb + bas) & (u32)kk) == 0);
    MERGE32(up);
    STORETILE(lds4);
  }
  __syncthreads();
  for (u32 uu = tid; uu < LCH / 4; uu += 256) gp4[uu] = lds4[U4(uu)];
}

// ---------------- K8: pair sorted X/T per (cluster,dim), weighted |diff| reduce
__global__ __launch_bounds__(256) void k_reduce(
    const u32* __restrict__ valX, const u32* __restrict__ valT,
    const int* __restrict__ pOffG, const int* __restrict__ mG,
    const float* __restrict__ wG, float* __restrict__ lossAcc, int Dbc)
{
  __shared__ int spOff[KCL + 1];
  __shared__ int sm[KCL];
  __shared__ float swt[KCL];
  __shared__ float red[256];
  int tid = threadIdx.x;
  if (tid <= KCL) spOff[tid] = pOffG[tid];
  if (tid < KCL) { sm[tid] = mG[tid]; swt[tid] = wG[tid]; }
  __syncthreads();
  int d = blockIdx.y;
  const u32* vx = valX + (size_t)d * SEG_STRIDE;
  const u32* vt = valT + (size_t)d * SEG_STRIDE;
  int P16 = spOff[KCL];
  float s = 0.f;
  for (int pos = blockIdx.x * 256 + tid; pos < P16; pos += gridDim.x * 256) {
    int c = 0;
#pragma unroll
    for (int cc = 1; cc < KCL; ++cc) c += (pos >= spOff[cc]) ? 1 : 0;
    int rel = pos - spOff[c];
    if (rel < sm[c]) {
      float a = dec_f(vx[pos]), b = dec_f(vt[pos]);
      s += fabsf(a - b) * swt[c];
    }
  }
  red[tid] = s;
  __syncthreads();
  for (int st = 128; st > 0; st >>= 1) {
    if (tid < st) red[tid] += red[tid + st];
    __syncthreads();
  }
  if (tid == 0) atomicAdd(lossAcc, red[0]);
}

// ---------------- K9: final scalar
__global__ void k_final(const float* __restrict__ lossAcc, const float* __restrict__ loss_fil,
                        float* __restrict__ out)
{
  out[0] = *lossAcc + *loss_fil;
}

extern "C" void kernel_launch(void* const* d_in, const int* in_sizes, int n_in,
                              void* d_out, int out_size, void* d_ws, size_t ws_size,
                              hipStream_t stream)
{
  const float* x       = (const float*)d_in[0];
  const float* centers = (const float*)d_in[1];
  const float* ftarget = (const float*)d_in[2];
  const float* tgt     = (const float*)d_in[3];
  const int*   predT   = (const int*)d_in[4];
  float* out = (float*)d_out;

  char* ws = (char*)d_ws;
  float* fill_sum = (float*)(ws + 0);       // 16 f (zeroed)
  float* lossAcc  = (float*)(ws + 64);      // zeroed
  float* loss_fil = (float*)(ws + 68);      // zeroed
  int*   m_buf    = (int*)(ws + 128);
  float* w_buf    = (float*)(ws + 192);
  int*   p_buf    = (int*)(ws + 256);
  int*   pOff     = (int*)(ws + 320);       // 17 ints
  int*   padOff   = (int*)(ws + 400);       // 17 ints
  u32* histX = (u32*)(ws + 512);            // 512*16*4 = 32768
  u32* histT = (u32*)(ws + 512 + 32768);
  u32* baseX = (u32*)(ws + 512 + 65536);
  u32* baseT = (u32*)(ws + 512 + 98304);
  int* predX = (int*)(ws + 131584);         // 524288
  int* rankX = (int*)(ws + 655872);
  int* rankT = (int*)(ws + 1180160);
  u32* vbase = (u32*)(ws + VOFF);

  size_t avail_elems = (ws_size > VOFF) ? ((ws_size - VOFF) / 4) : 0;
  int Db = (int)(avail_elems / (2ull * SEG_STRIDE));
  if (Db > DIMS) Db = DIMS;
  if (Db >= 4) Db &= ~3;
  if (Db < 1) Db = 1;

  hipMemsetAsync(ws, 0, 128, stream);
  k_assign<<<NBLK, 256, 0, stream>>>(x, centers, predT, predX, fill_sum, histX, histT);
  k_scan<<<1, 512, 0, stream>>>(histX, histT, baseX, baseT, fill_sum, ftarget,
                                m_buf, w_buf, p_buf, pOff, padOff, loss_fil);
  k_rank<<<NBLK, 256, 0, stream>>>(predX, predT, baseX, baseT, m_buf, rankX, rankT);

  for (int d0 = 0; d0 < DIMS; d0 += Db) {
    int Dbc = (Db < DIMS - d0) ? Db : (DIMS - d0);
    u32* valX = vbase;
    u32* valT = vbase + (size_t)Dbc * SEG_STRIDE;
    k_pad<<<dim3(16, 2 * Dbc), 256, 0, stream>>>(vbase, pOff, padOff, m_buf);
    k_scatter<<<NBLK, 256, 0, stream>>>(x, tgt, predX, predT, rankX, rankT, pOff,
                                        valX, valT, d0, Dbc);
    // chunks worst case: sum max(1, p/8192) <= 31 -> 40 x-blocks (extras early-exit)
    k_local_sort<<<dim3(40, 2 * Dbc), 256, 0, stream>>>(vbase, p_buf, pOff);
    // fallback merge stages for clusters with p > 8192 (early-exit when none)
    for (int kk = 2 * LCH; kk <= N_ROWS; kk <<= 1) {
      for (int j = kk >> 1; j >= LCH; j >>= 1)
        k_gpass<<<dim3(32, 2 * Dbc), 256, 0, stream>>>(vbase, p_buf, pOff, kk, j);
      // chunks needing finish <= sum(p)/LCH <= 32
      k_gfinish<<<dim3(32, 2 * Dbc), 256, 0, stream>>>(vbase, p_buf, pOff, kk);
    }
    k_reduce<<<dim3(32, Dbc), 256, 0, stream>>>(valX, valT, pOff, m_buf, w_buf, lossAcc, Dbc);
  }
  k_final<<<1, 1, 0, stream>>>(lossAcc, loss_fil, out);
}

// Round 10
// 838.780 us; speedup vs baseline: 1.9585x; 1.0073x over previous
//
#include <hip/hip_runtime.h>
#include <stdint.h>

#define N_ROWS 131072
#define DIMS 64
#define KCL 16
#define BETA 4.0f
#define NBLK 512            // N_ROWS / 256
#define LCH 8192            // elements per LDS sort chunk (8192 * 4B = 32KB LDS)
#define LST 512             // sort threads per block (8 waves)
#define SEG_STRIDE 263168   // u32 elements per (dim,side)
#define VOFF (1u<<21)

typedef unsigned long long u64;
typedef unsigned int u32;

__device__ __forceinline__ u32 enc_f(float f) {
  u32 u = __float_as_uint(f);
  return (u & 0x80000000u) ? ~u : (u | 0x80000000u);
}
__device__ __forceinline__ float dec_f(u32 e) {
  u32 u = (e & 0x80000000u) ? (e & 0x7FFFFFFFu) : ~e;
  return __uint_as_float(u);
}
// unit (uint4) granularity bank swizzle
__device__ __forceinline__ u32 U4(u32 u) { return u ^ ((u >> 3) & 7u); }

#define CS(a,b,dd) { u32 _mn = min(a,b), _mx = max(a,b); a = (dd)?_mn:_mx; b = (dd)?_mx:_mn; }
#define CSV(A,B,D) { CS(A.x,B.x,D) CS(A.y,B.y,D) CS(A.z,B.z,D) CS(A.w,B.w,D) }

// bitonic merge of 16 named regs, direction D (strides 8,4,2,1)
#define M16G(a,b,c,d,e,f,g,h,i2,j2,k2,l,m,n,o,p,D) \
  CS(a,i2,D) CS(b,j2,D) CS(c,k2,D) CS(d,l,D) CS(e,m,D) CS(f,n,D) CS(g,o,D) CS(h,p,D) \
  CS(a,e,D)  CS(b,f,D)  CS(c,g,D)  CS(d,h,D) CS(i2,m,D) CS(j2,n,D) CS(k2,o,D) CS(l,p,D) \
  CS(a,c,D)  CS(b,d,D)  CS(e,g,D)  CS(f,h,D) CS(i2,k2,D) CS(j2,l,D) CS(m,o,D) CS(n,p,D) \
  CS(a,b,D)  CS(c,d,D)  CS(e,f,D)  CS(g,h,D) CS(i2,j2,D) CS(k2,l,D) CS(m,n,D) CS(o,p,D)

// full bitonic sort of 16 named regs with final direction D
#define SORT16G(a,b,c,d,e,f,g,h,i2,j2,k2,l,m,n,o,p,D) \
  CS(a,b,D) CS(c,d,!(D)) CS(e,f,D) CS(g,h,!(D)) CS(i2,j2,D) CS(k2,l,!(D)) CS(m,n,D) CS(o,p,!(D)) \
  CS(a,c,D) CS(b,d,D) CS(e,g,!(D)) CS(f,h,!(D)) CS(i2,k2,D) CS(j2,l,D) CS(m,o,!(D)) CS(n,p,!(D)) \
  CS(a,b,D) CS(c,d,D) CS(e,f,!(D)) CS(g,h,!(D)) CS(i2,j2,D) CS(k2,l,D) CS(m,n,!(D)) CS(o,p,!(D)) \
  CS(a,e,D) CS(b,f,D) CS(c,g,D) CS(d,h,D) CS(i2,m,!(D)) CS(j2,n,!(D)) CS(k2,o,!(D)) CS(l,p,!(D)) \
  CS(a,c,D) CS(b,d,D) CS(e,g,D) CS(f,h,D) CS(i2,k2,!(D)) CS(j2,l,!(D)) CS(m,o,!(D)) CS(n,p,!(D)) \
  CS(a,b,D) CS(c,d,D) CS(e,f,D) CS(g,h,D) CS(i2,j2,!(D)) CS(k2,l,!(D)) CS(m,n,!(D)) CS(o,p,!(D)) \
  M16G(a,b,c,d,e,f,g,h,i2,j2,k2,l,m,n,o,p,D)

#define MERGE16F(D) M16G(r0,r1,r2,r3,r4,r5,r6,r7,r8,r9,r10,r11,r12,r13,r14,r15,D)
#define SORT16F(D)  SORT16G(r0,r1,r2,r3,r4,r5,r6,r7,r8,r9,r10,r11,r12,r13,r14,r15,D)

#define LOADTILE16(src) \
  { uint4 _a0=src[U4(ub+0)],_a1=src[U4(ub+1)],_a2=src[U4(ub+2)],_a3=src[U4(ub+3)]; \
    r0=_a0.x;r1=_a0.y;r2=_a0.z;r3=_a0.w; r4=_a1.x;r5=_a1.y;r6=_a1.z;r7=_a1.w; \
    r8=_a2.x;r9=_a2.y;r10=_a2.z;r11=_a2.w; r12=_a3.x;r13=_a3.y;r14=_a3.z;r15=_a3.w; }

#define STORETILE16(dst) \
  { dst[U4(ub+0)]=make_uint4(r0,r1,r2,r3);   dst[U4(ub+1)]=make_uint4(r4,r5,r6,r7); \
    dst[U4(ub+2)]=make_uint4(r8,r9,r10,r11); dst[U4(ub+3)]=make_uint4(r12,r13,r14,r15); }

// ---- fused LDS merge rounds for one bitonic stage k: strides k/2..16.
// 3-fuse j>=64 ({j,j/2,j/4}); 2-fuse j=32 ({32,16}); single j=16.
// Direction = ((gb+i)&k)==0 (constant over chunk when k > CH). Ends with barrier.
__device__ __forceinline__ void merge_stage_lds(uint4* lds4, u32 CH, u32 gb, u32 k, u32 tid)
{
  u32 j = k >> 1;
  if (j > (CH >> 1)) j = CH >> 1;
  while (j >= 16) {
    if (j >= 64) {                  // fused strides j, j/2, j/4 (all >= 16)
      u32 jq = j >> 2, ju = j >> 4; // jq elems, ju units between the 8 loads
      for (u32 p = tid << 2; p < (CH >> 3); p += LST * 4) {
        u32 col = p & (jq - 1);
        u32 i = ((p & ~(jq - 1)) << 3) | col;
        bool up = (((gb + i) & k) == 0);
        u32 bu = i >> 2;
        uint4 A0 = lds4[U4(bu)],          A1 = lds4[U4(bu + ju)],
              A2 = lds4[U4(bu + 2 * ju)], A3 = lds4[U4(bu + 3 * ju)],
              A4 = lds4[U4(bu + 4 * ju)], A5 = lds4[U4(bu + 5 * ju)],
              A6 = lds4[U4(bu + 6 * ju)], A7 = lds4[U4(bu + 7 * ju)];
        CSV(A0,A4,up) CSV(A1,A5,up) CSV(A2,A6,up) CSV(A3,A7,up)      // stride j
        CSV(A0,A2,up) CSV(A1,A3,up) CSV(A4,A6,up) CSV(A5,A7,up)      // stride j/2
        CSV(A0,A1,up) CSV(A2,A3,up) CSV(A4,A5,up) CSV(A6,A7,up)      // stride j/4
        lds4[U4(bu)] = A0;          lds4[U4(bu + ju)] = A1;
        lds4[U4(bu + 2 * ju)] = A2; lds4[U4(bu + 3 * ju)] = A3;
        lds4[U4(bu + 4 * ju)] = A4; lds4[U4(bu + 5 * ju)] = A5;
        lds4[U4(bu + 6 * ju)] = A6; lds4[U4(bu + 7 * ju)] = A7;
      }
      j >>= 3;
    } else if (j == 32) {           // fused strides 32, 16
      for (u32 p = tid << 2; p < (CH >> 2); p += LST * 4) {
        u32 col = p & 15u;
        u32 i = ((p & ~15u) << 2) | col;
        bool up = (((gb + i) & k) == 0);
        u32 bu = i >> 2;
        uint4 A0 = lds4[U4(bu)],     A1 = lds4[U4(bu + 4)],
              A2 = lds4[U4(bu + 8)], A3 = lds4[U4(bu + 12)];
        CSV(A0,A2,up) CSV(A1,A3,up)                                   // stride 32
        CSV(A0,A1,up) CSV(A2,A3,up)                                   // stride 16
        lds4[U4(bu)] = A0;     lds4[U4(bu + 4)] = A1;
        lds4[U4(bu + 8)] = A2; lds4[U4(bu + 12)] = A3;
      }
      j = 0;
    } else {                        // single stride 16
      for (u32 p = tid << 2; p < (CH >> 1); p += LST * 4) {
        u32 i = ((p & ~15u) << 1) | (p & 15u);
        bool up = (((gb + i) & k) == 0);
        u32 ua = U4(i >> 2), ub2 = U4((i + 16) >> 2);
        uint4 A = lds4[ua], B = lds4[ub2];
        CSV(A,B,up)
        lds4[ua] = A; lds4[ub2] = B;
      }
      j = 0;
    }
    __syncthreads();
  }
}

// ---------------- K1: cluster assign + softmax filling + per-block histograms
__global__ __launch_bounds__(256) void k_assign(
    const float* __restrict__ x, const float* __restrict__ centers,
    const int* __restrict__ predT, int* __restrict__ predX,
    float* __restrict__ fill_sum, u32* __restrict__ histX, u32* __restrict__ histT)
{
  __shared__ float c[KCL][DIMS];
  __shared__ float cn[KCL];
  __shared__ float fs[KCL];
  __shared__ u32 hx[KCL], ht[KCL];
  int tid = threadIdx.x;
  for (int t = tid; t < KCL * DIMS; t += 256) c[t / DIMS][t % DIMS] = centers[t];
  if (tid < KCL) { fs[tid] = 0.f; hx[tid] = 0; ht[tid] = 0; }
  __syncthreads();
  if (tid < KCL) {
    float s = 0.f;
    for (int d = 0; d < DIMS; ++d) s += c[tid][d] * c[tid][d];
    cn[tid] = s;
  }
  __syncthreads();
  int i = blockIdx.x * 256 + tid;
  const float4* xr = (const float4*)(x + (size_t)i * DIMS);
  float dot[KCL];
#pragma unroll
  for (int k = 0; k < KCL; ++k) dot[k] = 0.f;
  for (int t = 0; t < DIMS / 4; ++t) {
    float4 v = xr[t];
#pragma unroll
    for (int k = 0; k < KCL; ++k)
      dot[k] += v.x * c[k][4 * t] + v.y * c[k][4 * t + 1] + v.z * c[k][4 * t + 2] + v.w * c[k][4 * t + 3];
  }
  float sc[KCL];
  float smin = 3.0e38f; int kmin = 0;
#pragma unroll
  for (int k = 0; k < KCL; ++k) {
    sc[k] = cn[k] - 2.f * dot[k];
    if (sc[k] < smin) { smin = sc[k]; kmin = k; }
  }
  float e[KCL]; float esum = 0.f;
#pragma unroll
  for (int k = 0; k < KCL; ++k) { e[k] = expf(-BETA * (sc[k] - smin)); esum += e[k]; }
  float inv = 1.f / esum;
#pragma unroll
  for (int k = 0; k < KCL; ++k) atomicAdd(&fs[k], e[k] * inv);
  predX[i] = kmin;
  atomicAdd(&hx[kmin], 1u);
  atomicAdd(&ht[predT[i]], 1u);
  __syncthreads();
  if (tid < KCL) {
    histX[blockIdx.x * KCL + tid] = hx[tid];
    histT[blockIdx.x * KCL + tid] = ht[tid];
    atomicAdd(&fill_sum[tid], fs[tid]);
  }
}

// ---------------- K2: scan hists -> bases, totals, m, w, p, pOff, padOff, loss_fil
__global__ __launch_bounds__(512) void k_scan(
    const u32* __restrict__ histX, const u32* __restrict__ histT,
    u32* __restrict__ baseX, u32* __restrict__ baseT,
    const float* __restrict__ fill_sum, const float* __restrict__ ftarget,
    int* __restrict__ m_out, float* __restrict__ w_out,
    int* __restrict__ p_out, int* __restrict__ pOff_out, int* __restrict__ padOff_out,
    float* __restrict__ loss_fil)
{
  __shared__ u32 part[2][KCL][17];
  __shared__ u32 tot[2][KCL];
  __shared__ float sq[KCL];
  __shared__ int sp[KCL];
  __shared__ int smv[KCL];
  int tid = threadIdx.x;
  int side = tid >> 8;
  int rem = tid & 255;
  int c = rem >> 4;
  int sub = rem & 15;
  const u32* hist = side ? histT : histX;
  u32* base = side ? baseT : baseX;
  int b0 = sub * 32;
  u32 s = 0;
  for (int b = b0; b < b0 + 32; ++b) s += hist[b * KCL + c];
  part[side][c][sub] = s;
  __syncthreads();
  if (sub == 0) {
    u32 run = 0;
    for (int t = 0; t < 16; ++t) { u32 v = part[side][c][t]; part[side][c][t] = run; run += v; }
    tot[side][c] = run;
  }
  __syncthreads();
  u32 run = part[side][c][sub];
  for (int b = b0; b < b0 + 32; ++b) { base[b * KCL + c] = run; run += hist[b * KCL + c]; }
  if (tid < KCL) {
    int m = min((int)tot[0][tid], (int)tot[1][tid]);
    m_out[tid] = m;
    smv[tid] = m;
    w_out[tid] = (m > 0) ? 1.f / ((float)m * (float)DIMS) : 0.f;
    int pp = 32;
    while (pp < m) pp <<= 1;
    sp[tid] = pp;
    p_out[tid] = pp;
    float d = fill_sum[tid] / (float)N_ROWS - ftarget[tid];
    sq[tid] = d * d;
  }
  __syncthreads();
  if (tid == 0) {
    float s2 = 0.f;
    int acc = 0, pacc = 0;
    for (int k = 0; k < KCL; ++k) {
      s2 += sq[k];
      pOff_out[k] = acc;
      acc += sp[k];
      padOff_out[k] = pacc;
      pacc += sp[k] - smv[k];
    }
    pOff_out[KCL] = acc;
    padOff_out[KCL] = pacc;
    *loss_fil = s2 / (float)KCL;
  }
}

// ---------------- K3: ordered within-cluster rank (-1 if not kept)
__global__ __launch_bounds__(256) void k_rank(
    const int* __restrict__ predX, const int* __restrict__ predT,
    const u32* __restrict__ baseX, const u32* __restrict__ baseT,
    const int* __restrict__ m, int* __restrict__ rankX, int* __restrict__ rankT)
{
  __shared__ int wcX[4][KCL], wcT[4][KCL];
  int tid = threadIdx.x;
  int lane = tid & 63, wave = tid >> 6;
  int i = blockIdx.x * 256 + tid;
  int kx = predX[i], kt = predT[i];
  u64 below = (1ull << lane) - 1ull;
  int lrX = 0, lrT = 0;
  for (int cc = 0; cc < KCL; ++cc) {
    u64 mx = __ballot(kx == cc);
    u64 mt = __ballot(kt == cc);
    if (kx == cc) lrX = __popcll(mx & below);
    if (kt == cc) lrT = __popcll(mt & below);
    if (lane == 0) { wcX[wave][cc] = __popcll(mx); wcT[wave][cc] = __popcll(mt); }
  }
  __syncthreads();
  int wbX = 0, wbT = 0;
  for (int w2 = 0; w2 < wave; ++w2) { wbX += wcX[w2][kx]; wbT += wcT[w2][kt]; }
  int rX = (int)baseX[blockIdx.x * KCL + kx] + wbX + lrX;
  int rT = (int)baseT[blockIdx.x * KCL + kt] + wbT + lrT;
  rankX[i] = (rX < m[kx]) ? rX : -1;
  rankT[i] = (rT < m[kt]) ? rT : -1;
}

// ---------------- K3b: write 0xFF pads only into [pOff+m, pOff+p) per segment
__global__ __launch_bounds__(256) void k_pad(
    u32* __restrict__ vbase, const int* __restrict__ pOffG,
    const int* __restrict__ padOffG, const int* __restrict__ mG)
{
  __shared__ int sOff[KCL];
  __shared__ int sPad[KCL + 1];
  __shared__ int sM[KCL];
  int tid = threadIdx.x;
  if (tid < KCL) { sOff[tid] = pOffG[tid]; sM[tid] = mG[tid]; }
  if (tid <= KCL) sPad[tid] = padOffG[tid];
  __syncthreads();
  int tot = sPad[KCL];
  u32* seg = vbase + (size_t)blockIdx.y * SEG_STRIDE;
  for (int tt = blockIdx.x * 256 + tid; tt < tot; tt += gridDim.x * 256) {
    int c = 0;
#pragma unroll
    for (int cc = 1; cc < KCL; ++cc) c += (tt >= sPad[cc]) ? 1 : 0;
    seg[sOff[c] + sM[c] + (tt - sPad[c])] = 0xFFFFFFFFu;
  }
}

// ---------------- K4: scatter kept encoded values into cluster-partitioned dim arrays
__global__ __launch_bounds__(256) void k_scatter(
    const float* __restrict__ x, const float* __restrict__ tgt,
    const int* __restrict__ predX, const int* __restrict__ predT,
    const int* __restrict__ rankX, const int* __restrict__ rankT,
    const int* __restrict__ pOffG,
    u32* __restrict__ valX, u32* __restrict__ valT, int d0, int Dbc)
{
  __shared__ int spOff[KCL + 1];
  int tid = threadIdx.x;
  if (tid <= KCL) spOff[tid] = pOffG[tid];
  __syncthreads();
  int i = blockIdx.x * 256 + tid;
  int cx = predX[i], rx = rankX[i];
  int ct = predT[i], rt = rankT[i];
  bool vec = ((Dbc & 3) == 0);
  if (rx >= 0) {
    size_t pos = (size_t)spOff[cx] + rx;
    const float* xr = x + (size_t)i * DIMS + d0;
    if (vec) {
      const float4* x4 = (const float4*)xr;
      for (int d = 0; d < Dbc; d += 4) {
        float4 v = x4[d >> 2];
        valX[(size_t)(d + 0) * SEG_STRIDE + pos] = enc_f(v.x);
        valX[(size_t)(d + 1) * SEG_STRIDE + pos] = enc_f(v.y);
        valX[(size_t)(d + 2) * SEG_STRIDE + pos] = enc_f(v.z);
        valX[(size_t)(d + 3) * SEG_STRIDE + pos] = enc_f(v.w);
      }
    } else {
      for (int d = 0; d < Dbc; ++d) valX[(size_t)d * SEG_STRIDE + pos] = enc_f(xr[d]);
    }
  }
  if (rt >= 0) {
    size_t pos = (size_t)spOff[ct] + rt;
    const float* tr = tgt + (size_t)i * DIMS + d0;
    if (vec) {
      const float4* t4 = (const float4*)tr;
      for (int d = 0; d < Dbc; d += 4) {
        float4 v = t4[d >> 2];
        valT[(size_t)(d + 0) * SEG_STRIDE + pos] = enc_f(v.x);
        valT[(size_t)(d + 1) * SEG_STRIDE + pos] = enc_f(v.y);
        valT[(size_t)(d + 2) * SEG_STRIDE + pos] = enc_f(v.z);
        valT[(size_t)(d + 3) * SEG_STRIDE + pos] = enc_f(v.w);
      }
    } else {
      for (int d = 0; d < Dbc; ++d) valT[(size_t)d * SEG_STRIDE + pos] = enc_f(tr[d]);
    }
  }
}

// ---------------- K5: per-chunk LDS bitonic sort; 512 thr, 16 regs/thread, fused rounds
__global__ __launch_bounds__(LST, 8) void k_local_sort(
    u32* __restrict__ vbase, const int* __restrict__ pG, const int* __restrict__ pOffG)
{
  __shared__ __align__(16) u32 lds[LCH];
  uint4* lds4 = (uint4*)lds;
  int t = blockIdx.x, c = -1, sub = 0, acc = 0;
  for (int cc = 0; cc < KCL; ++cc) {
    int pc0 = pG[cc];
    int nc = (pc0 > LCH) ? (pc0 / LCH) : 1;
    if (t < acc + nc) { c = cc; sub = t - acc; break; }
    acc += nc;
  }
  if (c < 0) return;
  int pc = pG[c];
  u32 CH = (u32)min(pc, LCH);
  u32 gb = (u32)sub * (u32)LCH;
  u32* seg = vbase + (size_t)blockIdx.y * SEG_STRIDE + pOffG[c] + gb;
  uint4* gp4 = (uint4*)seg;
  u32 tid = threadIdx.x;
  u32 ub = tid << 2;           // first unit of this thread's 16-elem tile
  u32 bas = tid << 4;          // first element index
  bool act = (bas < CH);
  u32 r0,r1,r2,r3,r4,r5,r6,r7,r8,r9,r10,r11,r12,r13,r14,r15;

  // coalesced global -> LDS (swizzled)
  for (u32 uu = tid; (uu << 2) < CH; uu += LST) lds4[U4(uu)] = gp4[uu];
  __syncthreads();

  if (act) {
    LOADTILE16(lds4);
    bool D = (((gb + bas) & 16u) == 0u);
    SORT16F(D);
    STORETILE16(lds4);
  }
  __syncthreads();

  for (u32 k = 32; k <= CH; k <<= 1) {
    merge_stage_lds(lds4, CH, gb, k, tid);   // strides k/2..16, fused; ends with barrier
    if (act) {
      LOADTILE16(lds4);
      bool D = (((gb + bas) & k) == 0);
      MERGE16F(D);
      if (k < CH) {
        STORETILE16(lds4);
      } else {                 // final stage: straight to global
        gp4[ub + 0] = make_uint4(r0,r1,r2,r3);
        gp4[ub + 1] = make_uint4(r4,r5,r6,r7);
        gp4[ub + 2] = make_uint4(r8,r9,r10,r11);
        gp4[ub + 3] = make_uint4(r12,r13,r14,r15);
      }
    }
    __syncthreads();
  }
}

// ---------------- K6: global bitonic pass for big segments (b128, grid-stride, early-exit)
__global__ __launch_bounds__(256) void k_gpass(
    u32* __restrict__ vbase, const int* __restrict__ pG, const int* __restrict__ pOffG,
    int kk, int j)
{
  u32* base = vbase + (size_t)blockIdx.y * SEG_STRIDE;
  int pb[KCL]; int tot = 0;
#pragma unroll
  for (int c = 0; c < KCL; ++c) {
    pb[c] = tot;
    int pc = pG[c];
    if (pc >= kk) tot += pc >> 1;
  }
  for (int g4 = (blockIdx.x * 256 + threadIdx.x) << 2; g4 < tot; g4 += gridDim.x * 256 * 4) {
    int c = 0;
#pragma unroll
    for (int cc = 1; cc < KCL; ++cc) c += (g4 >= pb[cc]) ? 1 : 0;
    int u = g4 - pb[c];
    int i = ((u & ~(j - 1)) << 1) | (u & (j - 1));
    bool up = ((i & kk) == 0);
    u32* s2 = base + pOffG[c];
    uint4 A = *(const uint4*)(s2 + i);
    uint4 B = *(const uint4*)(s2 + i + j);
    CS(A.x, B.x, up) CS(A.y, B.y, up) CS(A.z, B.z, up) CS(A.w, B.w, up)
    *(uint4*)(s2 + i) = A;
    *(uint4*)(s2 + i + j) = B;
  }
}

// ---------------- K7: finish big-segment stage (strides <=4096) in LDS (early-exit)
__global__ __launch_bounds__(LST, 8) void k_gfinish(
    u32* __restrict__ vbase, const int* __restrict__ pG, const int* __restrict__ pOffG, int kk)
{
  __shared__ __align__(16) u32 lds[LCH];
  uint4* lds4 = (uint4*)lds;
  int t = blockIdx.x, c = -1, sub = 0, acc = 0;
  for (int cc = 0; cc < KCL; ++cc) {
    int pc = pG[cc];
    if (pc < kk) continue;
    int nc = pc / LCH;
    if (t < acc + nc) { c = cc; sub = t - acc; break; }
    acc += nc;
  }
  if (c < 0) return;
  u32 gb = (u32)sub * (u32)LCH;
  u32* seg = vbase + (size_t)blockIdx.y * SEG_STRIDE + pOffG[c] + gb;
  uint4* gp4 = (uint4*)seg;
  u32 tid = threadIdx.x;
  u32 ub = tid << 2;
  u32 bas = tid << 4;
  u32 r0,r1,r2,r3,r4,r5,r6,r7,r8,r9,r10,r11,r12,r13,r14,r15;

  for (u32 uu = tid; uu < LCH / 4; uu += LST) lds4[U4(uu)] = gp4[uu];
  __syncthreads();
  merge_stage_lds(lds4, LCH, gb, (u32)kk, tid);  // direction constant over chunk
  {
    LOADTILE16(lds4);
    bool up = (((gb + bas) & (u32)kk) == 0);
    MERGE16F(up);
    gp4[ub + 0] = make_uint4(r0,r1,r2,r3);       // straight to global
    gp4[ub + 1] = make_uint4(r4,r5,r6,r7);
    gp4[ub + 2] = make_uint4(r8,r9,r10,r11);
    gp4[ub + 3] = make_uint4(r12,r13,r14,r15);
  }
}

// ---------------- K8: pair sorted X/T per (cluster,dim), weighted |diff| reduce
__global__ __launch_bounds__(256) void k_reduce(
    const u32* __restrict__ valX, const u32* __restrict__ valT,
    const int* __restrict__ pOffG, const int* __restrict__ mG,
    const float* __restrict__ wG, float* __restrict__ lossAcc, int Dbc)
{
  __shared__ int spOff[KCL + 1];
  __shared__ int sm[KCL];
  __shared__ float swt[KCL];
  __shared__ float red[256];
  int tid = threadIdx.x;
  if (tid <= KCL) spOff[tid] = pOffG[tid];
  if (tid < KCL) { sm[tid] = mG[tid]; swt[tid] = wG[tid]; }
  __syncthreads();
  int d = blockIdx.y;
  const u32* vx = valX + (size_t)d * SEG_STRIDE;
  const u32* vt = valT + (size_t)d * SEG_STRIDE;
  int P16 = spOff[KCL];
  float s = 0.f;
  for (int pos = blockIdx.x * 256 + tid; pos < P16; pos += gridDim.x * 256) {
    int c = 0;
#pragma unroll
    for (int cc = 1; cc < KCL; ++cc) c += (pos >= spOff[cc]) ? 1 : 0;
    int rel = pos - spOff[c];
    if (rel < sm[c]) {
      float a = dec_f(vx[pos]), b = dec_f(vt[pos]);
      s += fabsf(a - b) * swt[c];
    }
  }
  red[tid] = s;
  __syncthreads();
  for (int st = 128; st > 0; st >>= 1) {
    if (tid < st) red[tid] += red[tid + st];
    __syncthreads();
  }
  if (tid == 0) atomicAdd(lossAcc, red[0]);
}

// ---------------- K9: final scalar
__global__ void k_final(const float* __restrict__ lossAcc, const float* __restrict__ loss_fil,
                        float* __restrict__ out)
{
  out[0] = *lossAcc + *loss_fil;
}

extern "C" void kernel_launch(void* const* d_in, const int* in_sizes, int n_in,
                              void* d_out, int out_size, void* d_ws, size_t ws_size,
                              hipStream_t stream)
{
  const float* x       = (const float*)d_in[0];
  const float* centers = (const float*)d_in[1];
  const float* ftarget = (const float*)d_in[2];
  const float* tgt     = (const float*)d_in[3];
  const int*   predT   = (const int*)d_in[4];
  float* out = (float*)d_out;

  char* ws = (char*)d_ws;
  float* fill_sum = (float*)(ws + 0);       // 16 f (zeroed)
  float* lossAcc  = (float*)(ws + 64);      // zeroed
  float* loss_fil = (float*)(ws + 68);      // zeroed
  int*   m_buf    = (int*)(ws + 128);
  float* w_buf    = (float*)(ws + 192);
  int*   p_buf    = (int*)(ws + 256);
  int*   pOff     = (int*)(ws + 320);       // 17 ints
  int*   padOff   = (int*)(ws + 400);       // 17 ints
  u32* histX = (u32*)(ws + 512);            // 512*16*4 = 32768
  u32* histT = (u32*)(ws + 512 + 32768);
  u32* baseX = (u32*)(ws + 512 + 65536);
  u32* baseT = (u32*)(ws + 512 + 98304);
  int* predX = (int*)(ws + 131584);         // 524288
  int* rankX = (int*)(ws + 655872);
  int* rankT = (int*)(ws + 1180160);
  u32* vbase = (u32*)(ws + VOFF);

  size_t avail_elems = (ws_size > VOFF) ? ((ws_size - VOFF) / 4) : 0;
  int Db = (int)(avail_elems / (2ull * SEG_STRIDE));
  if (Db > DIMS) Db = DIMS;
  if (Db >= 4) Db &= ~3;
  if (Db < 1) Db = 1;

  hipMemsetAsync(ws, 0, 128, stream);
  k_assign<<<NBLK, 256, 0, stream>>>(x, centers, predT, predX, fill_sum, histX, histT);
  k_scan<<<1, 512, 0, stream>>>(histX, histT, baseX, baseT, fill_sum, ftarget,
                                m_buf, w_buf, p_buf, pOff, padOff, loss_fil);
  k_rank<<<NBLK, 256, 0, stream>>>(predX, predT, baseX, baseT, m_buf, rankX, rankT);

  for (int d0 = 0; d0 < DIMS; d0 += Db) {
    int Dbc = (Db < DIMS - d0) ? Db : (DIMS - d0);
    u32* valX = vbase;
    u32* valT = vbase + (size_t)Dbc * SEG_STRIDE;
    k_pad<<<dim3(16, 2 * Dbc), 256, 0, stream>>>(vbase, pOff, padOff, m_buf);
    k_scatter<<<NBLK, 256, 0, stream>>>(x, tgt, predX, predT, rankX, rankT, pOff,
                                        valX, valT, d0, Dbc);
    // chunks worst case: sum max(1, p/8192) <= 31 -> 40 x-blocks (extras early-exit)
    k_local_sort<<<dim3(40, 2 * Dbc), LST, 0, stream>>>(vbase, p_buf, pOff);
    // fallback merge stages for clusters with p > 8192 (early-exit when none)
    for (int kk = 2 * LCH; kk <= N_ROWS; kk <<= 1) {
      for (int j = kk >> 1; j >= LCH; j >>= 1)
        k_gpass<<<dim3(32, 2 * Dbc), 256, 0, stream>>>(vbase, p_buf, pOff, kk, j);
      // chunks needing finish <= sum(p)/LCH <= 32
      k_gfinish<<<dim3(32, 2 * Dbc), LST, 0, stream>>>(vbase, p_buf, pOff, kk);
    }
    k_reduce<<<dim3(32, Dbc), 256, 0, stream>>>(valX, valT, pOff, m_buf, w_buf, lossAcc, Dbc);
  }
  k_final<<<1, 1, 0, stream>>>(lossAcc, loss_fil, out);
}